// Round 14
// baseline (362.233 us; speedup 1.0000x reference)
//
#include <hip/hip_runtime.h>
#include <hip/hip_bf16.h>

#define NP1 50176      // 224*224
#define NP2 12544      // 112*112
#define NPP 12996      // 114*114 zero-padded map

typedef __attribute__((ext_vector_type(8))) short short8;   // 8 bf16 = 4 VGPRs
typedef __attribute__((ext_vector_type(4))) float f32x4;

__device__ __forceinline__ unsigned short f2bu(float f){
  __hip_bfloat16 h = __float2bfloat16(f);
  return *reinterpret_cast<unsigned short*>(&h);
}
__device__ __forceinline__ float blo(unsigned u){ union{unsigned q; float f;} x; x.q = u<<16; return x.f; }
__device__ __forceinline__ float bhi(unsigned u){ union{unsigned q; float f;} x; x.q = u & 0xffff0000u; return x.f; }

// ---- workspace layout (float slots) ----
#define S_SUM1   0          // 128
#define S_SUM2   128        // 512
#define S_WOFF2  1280       // 73728 fp32 (k = n*256+c, oc padded 32)
#define S_W4F    75008      // 294912 (589824 bf16 frag-ready)
#define S_W2FH   369920     // 73728 (147456 bf16: w2 hi, frag-ready [kt][oc][kk], k=n*64+c)
#define S_W2FL   443648     // 73728 (147456 bf16: w2 lo)
#define S_OFFB   517376     // 451584 fp32 (NCHW)
#define S_PPAD   968960     // 1663488 fp32 (NCHW padded, raw pool; DEAD after k_affine1t -> convoff split-1 partial)
#define S_PHI    2632448    // 831744 (1663488 bf16 NHWC hi)
#define S_PLO    3464192    // 831744 (1663488 bf16 NHWC lo)
#define S_HPAD   4295936    // 6653952 fp32 (NHWC padded; post-affine values only on border band)
#define S_HPADL  10949888   // 3326976 (6653952 bf16 NHWC lo)
#define S_WOFFH  14276864   // 36864 (73728 bf16 frag-ready hi)
#define S_WOFFL  14313728   // 36864 (73728 bf16 frag-ready lo)
#define S_PB2    14350592   // 451584 fp32 (convoff split-2 partial)
#define S_HPADH  15014144   // 3326976 (6653952 bf16 NHWC hi)
#define WS_NEED_FLOATS 18341120ull
#define WS_NEED_BYTES  (WS_NEED_FLOATS*4ull)   // 73.4 MB

// ---- conv1+bias+ReLU + 2x2 avgpool (16 oc/block) with fused weight-prep prologue ----
// grid 392 = 2b * 4ocg * 49tiles. ppad values bit-identical.
__global__ __launch_bounds__(256) void k_conv1pool(
    const float* __restrict__ x, const float* __restrict__ w1, const float* __restrict__ b1,
    float* __restrict__ ppad, float* __restrict__ sum1,
    const float* __restrict__ w4, const float* __restrict__ woff, const float* __restrict__ w2,
    unsigned short* __restrict__ w4f, float* __restrict__ woff2,
    unsigned short* __restrict__ woffh, unsigned short* __restrict__ woffl,
    unsigned short* __restrict__ w2fh, unsigned short* __restrict__ w2fl){
  // ---- prologue: grid-stride over 884736 weight-prep jobs (same math as old k_prep) ----
  for(int t0 = blockIdx.x*256+threadIdx.x; t0 < 884736; t0 += 392*256){
    if(t0 < 589824){
      int kt = t0/8192; int r = t0 - kt*8192;
      int oc = r>>5, kk = r&31;
      int k = kt*32 + kk; int n = k>>8, c = k&255;
      w4f[t0] = f2bu(w4[oc*2304 + c*9 + n]);
    } else if(t0 < 663552){
      int i2 = t0 - 589824;                    // 73728
      int k = i2>>5, oc = i2&31;
      int n = k>>8, c = k&255;
      woff2[i2] = (oc<18) ? woff[oc*2304 + c*9 + n] : 0.f;
    } else if(t0 < 737280){
      int i3 = t0 - 663552;                    // 73728
      int kt = i3>>10; int r = i3 & 1023;
      int oc = r>>5, kk = r&31;
      int k = kt*32 + kk; int n = k>>8, c = k&255;
      float wv = (oc<18) ? woff[oc*2304 + c*9 + n] : 0.f;
      unsigned short hi = f2bu(wv);
      woffh[i3] = hi;
      woffl[i3] = f2bu(wv - blo(hi));
    } else {
      int i4 = t0 - 737280;                    // 147456
      int kt = i4/8192; int r = i4 - kt*8192;
      int oc = r>>5, kk = r&31;
      int k = kt*32 + kk; int n = k>>6, c = k&63;
      float wv = w2[oc*576 + c*9 + n];
      unsigned short hi = f2bu(wv);
      w2fh[i4] = hi;
      w2fl[i4] = f2bu(wv - blo(hi));
    }
  }
  // ---- main: conv1 + pool (bit-identical) ----
  __shared__ float xs[3*34*34];         // 13872 B
  __shared__ float ws[16*28];           // 16 oc x 27 taps (stride 28)
  __shared__ float wbia[16];
  __shared__ float red[4][32];          // [wave][stat*16+o]
  int bid = blockIdx.x;                 // 392
  int tile = bid % 49; int ocg = (bid/49) & 3; int b = bid/(49*4);
  int oc0 = ocg*16;
  int tu = tile/7, tv = tile - 7*(tile/7);
  int tid = threadIdx.x;
  int in0 = tu*32 - 1, jn0 = tv*32 - 1;
  for(int t=tid; t<3468; t+=256){
    int c = t/1156; int r2 = t - c*1156; int rr = r2/34; int cc = r2 - rr*34;
    int ii = in0+rr, jj = jn0+cc;
    xs[t] = (ii>=0 && ii<224 && jj>=0 && jj<224) ? x[(size_t)(b*3+c)*NP1 + ii*224+jj] : 0.f;
  }
  for(int t=tid; t<432; t+=256){
    int o = t/27, q = t - o*27;
    ws[o*28+q] = w1[(oc0+o)*27+q];
  }
  if(tid<16) wbia[tid] = b1[oc0+tid];
  __syncthreads();
  int u = tid>>4, v = tid&15;           // pooled coords in tile
  float xw[3][4][4];
  #pragma unroll
  for(int c=0;c<3;c++)
    #pragma unroll
    for(int r=0;r<4;r++)
      #pragma unroll
      for(int cc=0;cc<4;cc++)
        xw[c][r][cc] = xs[c*1156 + (2*u+r)*34 + (2*v+cc)];
  float s1o[16], s2o[16];
  int U = tu*16+u, V = tv*16+v;
  size_t prow = (size_t)(U+1)*114 + (V+1);
  #pragma unroll 1
  for(int o=0;o<16;o++){
    float w27[27];
    #pragma unroll
    for(int q=0;q<27;q++) w27[q] = ws[o*28+q];
    float bia = wbia[o];
    float pl=0.f, s1=0.f, s2=0.f;
    #pragma unroll
    for(int dy=0;dy<2;dy++){
      #pragma unroll
      for(int dx=0;dx<2;dx++){
        float acc = bia;
        #pragma unroll
        for(int c=0;c<3;c++)
          #pragma unroll
          for(int kh=0;kh<3;kh++)
            #pragma unroll
            for(int kw=0;kw<3;kw++)
              acc += xw[c][dy+kh][dx+kw] * w27[c*9+kh*3+kw];
        acc = fmaxf(acc, 0.f);          // relu BEFORE BN
        pl += acc; s1 += acc; s2 += acc*acc;
      }
    }
    ppad[(size_t)(b*64+oc0+o)*NPP + prow] = 0.25f*pl;
    s1o[o] = s1; s2o[o] = s2;
  }
  const int lane = tid&63, wv = tid>>6;
  #pragma unroll 1
  for(int o=0;o<16;o++){
    float a = s1o[o], c2 = s2o[o];
    #pragma unroll
    for(int off=32; off; off>>=1){
      a  += __shfl_down(a,  off, 64);
      c2 += __shfl_down(c2, off, 64);
    }
    if(lane==0){ red[wv][o] = a; red[wv][16+o] = c2; }
  }
  __syncthreads();
  if(tid<32){
    int o = tid&15, st = tid>>4;
    float v4 = ((red[0][st*16+o] + red[1][st*16+o]) + red[2][st*16+o]) + red[3][st*16+o];
    atomicAdd(&sum1[st*64 + oc0 + o], v4);
  }
}

// ---- BN1 stats (per-block, redundant) + affine + NCHW->NHWC + hi/lo bf16; zero border ----
__global__ __launch_bounds__(256) void k_affine1t(const float* __restrict__ ppad,
        const float* __restrict__ sum1, const float* __restrict__ g1,
        const float* __restrict__ be1,
        unsigned short* __restrict__ phi, unsigned short* __restrict__ plo){
  __shared__ float ls[64*65];
  __shared__ float sc_l[64], sh_l[64];
  int bid = blockIdx.x;                 // 408 = 2*204
  int b = bid/204; int pp0 = (bid - b*204)*64;
  int tid = threadIdx.x;
  if(tid < 64){                         // bit-identical to old k_fin1
    float n = 2.f*(float)NP1;
    float mean = sum1[tid]/n;
    float var  = sum1[64+tid]/n - mean*mean;
    float sc = g1[tid]/sqrtf(var + 1e-5f);
    sc_l[tid] = sc;
    sh_l[tid] = be1[tid] - mean*sc;
  }
  __syncthreads();
  #pragma unroll
  for(int it=0; it<16; it++){
    int t = it*256 + tid;
    int c = t>>6, q = t&63;
    int pp = pp0 + q;
    float v = 0.f;
    if(pp < NPP){
      int row = pp/114, col = pp - row*114;
      if(row>=1 && row<=112 && col>=1 && col<=112)
        v = sc_l[c]*ppad[(size_t)(b*64+c)*NPP + pp] + sh_l[c];
    }
    ls[c*65+q] = v;
  }
  __syncthreads();
  #pragma unroll
  for(int it=0; it<8; it++){            // 2 channels per thread -> packed 4B stores
    int t = it*256 + tid;               // 2048 slots = 64 qloc x 32 cpair
    int qloc = t >> 5; int cp = (t & 31) * 2;
    int pp = pp0 + qloc;
    if(pp < NPP){
      float v0 = ls[cp*65 + qloc], v1 = ls[(cp+1)*65 + qloc];
      unsigned short h0 = f2bu(v0), h1 = f2bu(v1);
      unsigned oh = (unsigned)h0 | ((unsigned)h1<<16);
      unsigned ol = (unsigned)f2bu(v0 - blo(h0)) | ((unsigned)f2bu(v1 - blo(h1))<<16);
      *(unsigned*)&phi[((size_t)b*NPP + pp)*64 + cp] = oh;
      *(unsigned*)&plo[((size_t)b*NPP + pp)*64 + cp] = ol;
    }
  }
}

// ---- conv2: MFMA bf16x2, M-tile 64, N=256, K=576; BN2 partial stats fused in epilogue ----
__global__ __launch_bounds__(256) void k_conv2(
    const unsigned short* __restrict__ phi, const unsigned short* __restrict__ plo,
    const unsigned short* __restrict__ w2fh, const unsigned short* __restrict__ w2fl,
    const float* __restrict__ b2, float* __restrict__ hpad, float* __restrict__ sum2){
  __shared__ float smemf[8800];   // pp_tbl[576 ints] | af(5120 floats) ∪ tb(8224 floats)
  int*  pp_tbl = (int*)smemf;
  unsigned short* afh0 = (unsigned short*)(smemf + 576);    // 2*64*40 shorts = 2560 floats
  unsigned short* afl0 = (unsigned short*)(smemf + 576 + 2560);
  float* tb = smemf + 576;
  const int tid = threadIdx.x;
  const int wave = tid>>6, lane = tid&63;
  const int sidx = (blockIdx.x & 7)*49 + (blockIdx.x >> 3);  // XCD swizzle, grid 392
  const int pix0 = sidx*64;
  const int b = pix0/NP2, ij0 = pix0 - b*NP2;

  for(int t=tid; t<576; t+=256){
    int p = t/9, n = t - 9*(t/9);
    int ij = ij0+p; int i = ij/112, j = ij - i*112;
    pp_tbl[p*9+n] = (i + n/3)*114 + (j + n%3);
  }
  const int px_g = tid>>2;
  const int coff = (tid&3)*8;
  const unsigned short* ph_b = phi + (size_t)b*NPP*64;
  const unsigned short* pl_b = plo + (size_t)b*NPP*64;

  f32x4 acc[4][4] = {};
  __syncthreads();

  auto STAGE = [&](int kt, int buf){
    int n = kt>>1; int cb = ((kt&1)<<5) + coff;
    int pp = pp_tbl[px_g*9 + n];
    *(uint4*)&afh0[buf*2560 + px_g*40 + coff] = *(const uint4*)(ph_b + (size_t)pp*64 + cb);
    *(uint4*)&afl0[buf*2560 + px_g*40 + coff] = *(const uint4*)(pl_b + (size_t)pp*64 + cb);
  };

  const int klo = (lane>>4)<<3;
  STAGE(0, 0);
  for(int kt=0; kt<18; kt++){
    __syncthreads();
    if(kt+1 < 18) STAGE(kt+1, (kt+1)&1);
    const unsigned short* abh = afh0 + (kt&1)*2560;
    const unsigned short* abl = afl0 + (kt&1)*2560;
    short8 aH[4], aL[4];
    #pragma unroll
    for(int mf=0; mf<4; mf++){
      aH[mf] = *(const short8*)&abh[(mf*16 + (lane&15))*40 + klo];
      aL[mf] = *(const short8*)&abl[(mf*16 + (lane&15))*40 + klo];
    }
    __builtin_amdgcn_s_setprio(1);      // T5: favor MFMA wave vs staging waves of co-resident blocks
    #pragma unroll
    for(int nf=0; nf<4; nf++){
      int oc = wave*64 + nf*16 + (lane&15);
      short8 bH = *(const short8*)&w2fh[(size_t)kt*8192 + oc*32 + klo];
      short8 bL = *(const short8*)&w2fl[(size_t)kt*8192 + oc*32 + klo];
      #pragma unroll
      for(int mf=0; mf<4; mf++){
        acc[mf][nf] = __builtin_amdgcn_mfma_f32_16x16x32_bf16(aH[mf], bH, acc[mf][nf], 0,0,0);
        acc[mf][nf] = __builtin_amdgcn_mfma_f32_16x16x32_bf16(aH[mf], bL, acc[mf][nf], 0,0,0);
        acc[mf][nf] = __builtin_amdgcn_mfma_f32_16x16x32_bf16(aL[mf], bH, acc[mf][nf], 0,0,0);
      }
    }
    __builtin_amdgcn_s_setprio(0);
  }
  // epilogue: two 32-px halves through tb (bias+relu), NHWC float4 stores + BN2 partials
  const int row0 = (lane>>4)<<2, col = lane&15;
  float s1q[4] = {0.f,0.f,0.f,0.f}, s2q[4] = {0.f,0.f,0.f,0.f};
  for(int half=0; half<2; half++){
    __syncthreads();
    #pragma unroll
    for(int m2=0; m2<2; m2++){
      int mf = half*2 + m2;
      #pragma unroll
      for(int nf=0; nf<4; nf++){
        int oc = wave*64 + nf*16 + col;
        #pragma unroll
        for(int r=0;r<4;r++) tb[(m2*16 + row0 + r)*257 + oc] = acc[mf][nf][r];
      }
    }
    __syncthreads();
    #pragma unroll
    for(int it=0; it<8; it++){
      int id = it*256 + tid;
      int pxl = id>>6, oc4 = id&63;            // oc4 == tid&63 (constant per thread)
      int px = half*32 + pxl;
      int ij = ij0+px; int i = ij/112, j = ij - i*112;
      int pp = (i+1)*114 + (j+1);
      float4 v;
      v.x = fmaxf(tb[pxl*257 + oc4*4+0] + b2[oc4*4+0], 0.f);
      v.y = fmaxf(tb[pxl*257 + oc4*4+1] + b2[oc4*4+1], 0.f);
      v.z = fmaxf(tb[pxl*257 + oc4*4+2] + b2[oc4*4+2], 0.f);
      v.w = fmaxf(tb[pxl*257 + oc4*4+3] + b2[oc4*4+3], 0.f);
      *(float4*)&hpad[((size_t)b*NPP + pp)*256 + oc4*4] = v;   // raw (pre-BN2)
      s1q[0] += v.x; s2q[0] += v.x*v.x;
      s1q[1] += v.y; s2q[1] += v.y*v.y;
      s1q[2] += v.z; s2q[2] += v.z*v.z;
      s1q[3] += v.w; s2q[3] += v.w*v.w;
    }
  }
  // block-level BN2 partial reduce through tb, one atomic pair per oc
  __syncthreads();
  #pragma unroll
  for(int q=0;q<4;q++){ tb[tid*4+q] = s1q[q]; tb[1024 + tid*4+q] = s2q[q]; }
  __syncthreads();
  {
    int oc = tid;                               // 256 ocs
    float s1 = ((tb[oc] + tb[256+oc]) + tb[512+oc]) + tb[768+oc];
    float s2 = ((tb[1024+oc] + tb[1280+oc]) + tb[1536+oc]) + tb[1792+oc];
    atomicAdd(&sum2[oc], s1); atomicAdd(&sum2[256+oc], s2);
  }
}

// ---- BN2 stats (per-block, redundant) + affine, 4-ch vectorized; bf16 hi/lo; band fp32 ----
__global__ __launch_bounds__(256) void k_affine2(float* __restrict__ hpad,
                          const float* __restrict__ sum2, const float* __restrict__ g2,
                          const float* __restrict__ be2,
                          unsigned short* __restrict__ hpadh, unsigned short* __restrict__ hpadl){
  __shared__ float sc_l[256], sh_l[256];
  int tid = threadIdx.x;
  {                                     // bit-identical to old k_fin2
    float n = 2.f*(float)NP2;
    float mean = sum2[tid]/n;
    float var  = sum2[256+tid]/n - mean*mean;
    float sc = g2[tid]/sqrtf(var + 1e-5f);
    sc_l[tid] = sc;
    sh_l[tid] = be2[tid] - mean*sc;
  }
  __syncthreads();
  int idx = blockIdx.x*256+tid;            // 1663488 = 6498*256
  int c4 = (idx & 63) << 2;                // 0,4,..252
  int pi = idx >> 6;                       // 0..25991
  int pp = pi % NPP;
  int row = pp/114, col = pp - row*114;
  bool in = (row>=1 && row<=112 && col>=1 && col<=112);
  float4 h = *(const float4*)&hpad[(size_t)pi*256 + c4];
  float4 v;
  v.x = in ? (sc_l[c4+0]*h.x + sh_l[c4+0]) : 0.f;
  v.y = in ? (sc_l[c4+1]*h.y + sh_l[c4+1]) : 0.f;
  v.z = in ? (sc_l[c4+2]*h.z + sh_l[c4+2]) : 0.f;
  v.w = in ? (sc_l[c4+3]*h.w + sh_l[c4+3]) : 0.f;
  // fp32 hpad is only consumed by k_offpost's offfix half on the border band
  bool band = (row<6) || (row>107) || (col<6) || (col>107);
  if(band) *(float4*)&hpad[(size_t)pi*256 + c4] = v;
  unsigned short hx = f2bu(v.x), hy = f2bu(v.y), hz = f2bu(v.z), hw = f2bu(v.w);
  uint2 oh, ol;
  oh.x = (unsigned)hx | ((unsigned)hy<<16);
  oh.y = (unsigned)hz | ((unsigned)hw<<16);
  ol.x = (unsigned)f2bu(v.x - blo(hx)) | ((unsigned)f2bu(v.y - blo(hy))<<16);
  ol.y = (unsigned)f2bu(v.z - blo(hz)) | ((unsigned)f2bu(v.w - blo(hw))<<16);
  *(uint2*)&hpadh[(size_t)pi*256 + c4] = oh;
  *(uint2*)&hpadl[(size_t)pi*256 + c4] = ol;
}

// ---- offset conv, tap-split-K MFMA: 3 splits x 3 taps, grid 1176 = 8 xcd * 147 ----
__global__ __launch_bounds__(256) void k_convoff_mfma(
    const unsigned short* __restrict__ hpadh, const unsigned short* __restrict__ hpadl,
    const unsigned short* __restrict__ woffh, const unsigned short* __restrict__ woffl,
    float* __restrict__ p0, float* __restrict__ p1, float* __restrict__ p2){
  __shared__ int pp_tbl[192];                              // 64 px x 3 taps
  __shared__ __align__(16) unsigned short afh[2][64*72];   // 18432 B
  __shared__ __align__(16) unsigned short afl[2][64*72];   // 18432 B
  const int tid = threadIdx.x;
  const int wave = tid>>6, lane = tid&63;
  const int g = blockIdx.x;
  const int xcd = g & 7;
  const int rr  = g >> 3;               // 0..146
  const int split = rr % 3;             // k-split: taps split*3 .. +2
  const int sstrip = rr / 3;            // 0..48
  const int strip = xcd*49 + sstrip;    // 0..391
  const int pix0 = strip*64;
  const int b = pix0/NP2, ij0 = pix0 - b*NP2;
  const int n0 = split*3;

  for(int t=tid; t<192; t+=256){
    int p = t/3, nl = t - 3*(t/3);
    int ij = ij0+p; int i = ij/112, j = ij - i*112;
    int n = n0 + nl;
    pp_tbl[p*3+nl] = (i + n/3)*114 + (j + n%3);
  }
  const int px_g = tid>>2;              // 64 px, 4 thr/px
  const int coff = (tid&3)*16;          // 16-short (32B) slice of the 64-k phase
  const unsigned short* ph_b = hpadh + (size_t)b*NPP*256;
  const unsigned short* pl_b = hpadl + (size_t)b*NPP*256;
  const int r15 = lane&15, klo = (lane>>4)<<3;

  f32x4 acc[2] = {};
  __syncthreads();                      // pp_tbl ready

  auto STAGE = [&](int ph, int buf){    // ph = nl*4 + q : stages k = q*64..+63 of tap n0+nl
    int nl = ph>>2, q = ph&3;
    int pp = pp_tbl[px_g*3 + nl];
    int cb = q*64 + coff;
    uint4 h0 = *(const uint4*)(ph_b + (size_t)pp*256 + cb);
    uint4 h1 = *(const uint4*)(ph_b + (size_t)pp*256 + cb + 8);
    uint4 l0 = *(const uint4*)(pl_b + (size_t)pp*256 + cb);
    uint4 l1 = *(const uint4*)(pl_b + (size_t)pp*256 + cb + 8);
    *(uint4*)&afh[buf][px_g*72 + coff    ] = h0;
    *(uint4*)&afh[buf][px_g*72 + coff + 8] = h1;
    *(uint4*)&afl[buf][px_g*72 + coff    ] = l0;
    *(uint4*)&afl[buf][px_g*72 + coff + 8] = l1;
  };

  STAGE(0, 0);
  for(int ph=0; ph<12; ph++){
    __syncthreads();
    if(ph+1 < 12) STAGE(ph+1, (ph+1)&1);
    const unsigned short* ah = &afh[ph&1][(wave*16 + r15)*72];
    const unsigned short* al = &afl[ph&1][(wave*16 + r15)*72];
    const int n = n0 + (ph>>2), q = ph&3;
    __builtin_amdgcn_s_setprio(1);      // T5
    #pragma unroll
    for(int half=0; half<2; half++){
      int kt = n*8 + q*2 + half;        // global k-tile index (B layout unchanged)
      short8 aH = *(const short8*)&ah[half*32 + klo];
      short8 aL = *(const short8*)&al[half*32 + klo];
      #pragma unroll
      for(int nf=0; nf<2; nf++){
        int oc = nf*16 + r15;
        short8 bH = *(const short8*)&woffh[(size_t)kt*1024 + oc*32 + klo];
        short8 bL = *(const short8*)&woffl[(size_t)kt*1024 + oc*32 + klo];
        acc[nf] = __builtin_amdgcn_mfma_f32_16x16x32_bf16(aH, bH, acc[nf], 0,0,0);
        acc[nf] = __builtin_amdgcn_mfma_f32_16x16x32_bf16(aH, bL, acc[nf], 0,0,0);
        acc[nf] = __builtin_amdgcn_mfma_f32_16x16x32_bf16(aL, bH, acc[nf], 0,0,0);
      }
    }
    __builtin_amdgcn_s_setprio(0);
  }
  float* dst = (split==0) ? p0 : (split==1) ? p1 : p2;
  const int row0 = (lane>>4)<<2;
  #pragma unroll
  for(int nf=0; nf<2; nf++){
    int oc = nf*16 + r15;
    if(oc < 18)
      *(f32x4*)(dst + (size_t)(b*18+oc)*NP2 + ij0 + wave*16 + row0) = acc[nf];
  }
}

// ---- merged offset post-pass: blocks 0..440 = 3-partial reduce + bias (skipping the
// exact-band pixels), blocks 441..767 = exact-fp32 border recompute. Write-sets disjoint.
__global__ __launch_bounds__(256) void k_offpost(float* __restrict__ offb,
        const float* __restrict__ p1, const float* __restrict__ p2,
        const float* __restrict__ boff, const float* __restrict__ hpad,
        const float* __restrict__ woff2){
  int bb = blockIdx.x;                  // 768 = 441 red + 327 fix
  if(bb < 441){
    int i4 = bb*256+threadIdx.x;        // 112896
    int idx = i4*4;
    int oc = (idx/NP2) % 18;
    int ij = idx % NP2;
    int i = ij/112, j0 = ij - i*112;    // 4-chunk stays within one row (112%4==0)
    float bo = boff[oc];
    f32x4 a  = *(const f32x4*)&offb[idx];
    f32x4 q1 = *(const f32x4*)&p1[idx];
    f32x4 q2 = *(const f32x4*)&p2[idx];
    float r[4];
    r[0] = ((a.x + q1.x) + q2.x) + bo;
    r[1] = ((a.y + q1.y) + q2.y) + bo;
    r[2] = ((a.z + q1.z) + q2.z) + bo;
    r[3] = ((a.w + q1.w) + q2.w) + bo;
    bool rowband = (i<3) || (i>108);
    if(!rowband && j0>=3 && (j0+3)<=108){
      f32x4 o; o.x=r[0]; o.y=r[1]; o.z=r[2]; o.w=r[3];
      *(f32x4*)&offb[idx] = o;
    } else {
      #pragma unroll
      for(int e=0;e<4;e++){
        int j = j0+e;
        bool band = rowband || (j<3) || (j>108);
        if(!band) offb[idx+e] = r[e];
      }
    }
  } else {
    int idx = (bb-441)*256 + threadIdx.x;   // 327*256 = 83712 = 2*1308*32
    if(idx >= 83712) return;
    int oc = idx & 31;
    int pid = idx >> 5;                     // 0..2615
    int b = pid / 1308; int t = pid - b*1308;
    int i, j;
    if(t < 672){                            // full rows 0,1,2,109,110,111
      int r = t/112; i = (r<3) ? r : 106+r; j = t - (t/112)*112;
    } else {                                // cols 0,1,2,109,110,111 of rows 3..108
      int u = t - 672; i = 3 + u/6; int c6 = u - 6*(u/6);
      j = (c6<3) ? c6 : 106+c6;
    }
    const float* hb = hpad + (size_t)b*NPP*256;
    float a0=0.f, a1=0.f, a2=0.f, a3=0.f;   // 4 independent chains
    for(int n=0;n<9;n++){
      const float* ap = hb + (size_t)((i + n/3)*114 + (j + n%3))*256;
      const float* wp = woff2 + (size_t)n*256*32 + oc;
      #pragma unroll 4
      for(int c=0;c<256;c+=4){
        float4 a = *(const float4*)(ap + c);
        a0 = fmaf(a.x, wp[(c+0)*32], a0);
        a1 = fmaf(a.y, wp[(c+1)*32], a1);
        a2 = fmaf(a.z, wp[(c+2)*32], a2);
        a3 = fmaf(a.w, wp[(c+3)*32], a3);
      }
    }
    if(oc < 18)
      offb[(size_t)(b*18+oc)*NP2 + i*112 + j] = ((a0+a1)+(a2+a3)) + boff[oc];
  }
}

// ---- deformable conv: MFMA bf16, M-tile 64, 36 merged phases (k=64 each), grid 392 ----
__global__ __launch_bounds__(256) void k_deform(
    const unsigned short* __restrict__ hpadh,       // NHWC bf16, affine'd, zero border
    const float* __restrict__ offb,                 // NCHW fp32
    const unsigned short* __restrict__ w4f,         // frag-ready bf16 [72][256][32]
    float* __restrict__ out){
  __shared__ int   gidx[64][9][4];
  __shared__ float gwt [64][9][4];
  __shared__ __align__(16) unsigned short afrag[2][64*72];  // px stride 72 shorts (bank-safe)
  const int tid = threadIdx.x;
  const int wave = tid>>6, lane = tid&63;
  const int sidx = (blockIdx.x & 7)*49 + (blockIdx.x >> 3);
  const int pix0 = sidx*64;
  const int b = pix0/NP2, ij0 = pix0 - b*NP2;

  for(int t=tid; t<576; t+=256){
    int p = t/9, n = t - 9*(t/9);
    int ij = ij0+p; int i = ij/112, j = ij - i*112;
    float ox = offb[(size_t)(b*18 + 2*n  )*NP2 + ij];
    float oy = offb[(size_t)(b*18 + 2*n+1)*NP2 + ij];
    float px = (float)(i + n/3) + ox;
    float py = (float)(j + n%3) + oy;
    float fpx = floorf(px), fpy = floorf(py);
    float qltxf = fminf(fmaxf(fpx,     0.f),113.f);
    float qltyf = fminf(fmaxf(fpy,     0.f),113.f);
    float qrbxf = fminf(fmaxf(fpx+1.f, 0.f),113.f);
    float qrbyf = fminf(fmaxf(fpy+1.f, 0.f),113.f);
    int qltx=(int)qltxf, qlty=(int)qltyf, qrbx=(int)qrbxf, qrby=(int)qrbyf;
    bool mx = (px<1.f)||(px>112.f);
    bool my = (py<1.f)||(py>112.f);
    float pxc = fminf(fmaxf(mx?fpx:px, 0.f),113.f);
    float pyc = fminf(fmaxf(my?fpy:py, 0.f),113.f);
    float glt = (1.f+(qltxf-pxc))*(1.f+(qltyf-pyc));
    float grb = (1.f-(qrbxf-pxc))*(1.f-(qrbyf-pyc));
    float glb = (1.f+(qltxf-pxc))*(1.f-(qrbyf-pyc));
    float grt = (1.f-(qrbxf-pxc))*(1.f+(qltyf-pyc));
    gidx[p][n][0]=qltx*114+qlty; gwt[p][n][0]=glt;
    gidx[p][n][1]=qrbx*114+qrby; gwt[p][n][1]=grb;
    gidx[p][n][2]=qltx*114+qrby; gwt[p][n][2]=glb;  // (lt_x, rb_y)
    gidx[p][n][3]=qrbx*114+qlty; gwt[p][n][3]=grt;  // (rb_x, lt_y)
  }

  const int px_g   = tid>>2;            // 0..63
  const int coff_g = (tid&3)*8;         // 8-channel slice within each 32-ch k-chunk
  const unsigned short* hb = hpadh + (size_t)b*NPP*256;

  f32x4 acc[4][4] = {};
  __syncthreads();

  // phase ph covers tap n = ph>>2, channels (ph&3)*64 .. +63 (= global kt pair n*8+(ph&3)*2, +1)
  auto GATHER = [&](int ph, int buf){
    int n = ph>>2; int qb = (ph&3)<<6;
    const int*   gi = gidx[px_g][n];
    const float* gw = gwt[px_g][n];
    int i0 = gi[0], i1 = gi[1], i2 = gi[2], i3 = gi[3];
    float w0 = gw[0], w1 = gw[1], w2 = gw[2], w3 = gw[3];
    #pragma unroll
    for(int h=0; h<2; h++){
      int cb = qb + h*32 + coff_g;
      f32x4 va = {0.f,0.f,0.f,0.f}, vb = {0.f,0.f,0.f,0.f};
      const uint4 u0 = *(const uint4*)(hb + (size_t)i0*256 + cb);
      const uint4 u1 = *(const uint4*)(hb + (size_t)i1*256 + cb);
      const uint4 u2 = *(const uint4*)(hb + (size_t)i2*256 + cb);
      const uint4 u3 = *(const uint4*)(hb + (size_t)i3*256 + cb);
      // per-channel corner order 0,1,2,3 — identical to the 32-k version
      va.x = fmaf(w0, blo(u0.x), va.x); va.y = fmaf(w0, bhi(u0.x), va.y);
      va.z = fmaf(w0, blo(u0.y), va.z); va.w = fmaf(w0, bhi(u0.y), va.w);
      vb.x = fmaf(w0, blo(u0.z), vb.x); vb.y = fmaf(w0, bhi(u0.z), vb.y);
      vb.z = fmaf(w0, blo(u0.w), vb.z); vb.w = fmaf(w0, bhi(u0.w), vb.w);
      va.x = fmaf(w1, blo(u1.x), va.x); va.y = fmaf(w1, bhi(u1.x), va.y);
      va.z = fmaf(w1, blo(u1.y), va.z); va.w = fmaf(w1, bhi(u1.y), va.w);
      vb.x = fmaf(w1, blo(u1.z), vb.x); vb.y = fmaf(w1, bhi(u1.z), vb.y);
      vb.z = fmaf(w1, blo(u1.w), vb.z); vb.w = fmaf(w1, bhi(u1.w), vb.w);
      va.x = fmaf(w2, blo(u2.x), va.x); va.y = fmaf(w2, bhi(u2.x), va.y);
      va.z = fmaf(w2, blo(u2.y), va.z); va.w = fmaf(w2, bhi(u2.y), va.w);
      vb.x = fmaf(w2, blo(u2.z), vb.x); vb.y = fmaf(w2, bhi(u2.z), vb.y);
      vb.z = fmaf(w2, blo(u2.w), vb.z); vb.w = fmaf(w2, bhi(u2.w), vb.w);
      va.x = fmaf(w3, blo(u3.x), va.x); va.y = fmaf(w3, bhi(u3.x), va.y);
      va.z = fmaf(w3, blo(u3.y), va.z); va.w = fmaf(w3, bhi(u3.y), va.w);
      vb.x = fmaf(w3, blo(u3.z), vb.x); vb.y = fmaf(w3, bhi(u3.z), vb.y);
      vb.z = fmaf(w3, blo(u3.w), vb.z); vb.w = fmaf(w3, bhi(u3.w), vb.w);
      uint4 o;
      o.x = (unsigned)f2bu(va.x) | ((unsigned)f2bu(va.y)<<16);
      o.y = (unsigned)f2bu(va.z) | ((unsigned)f2bu(va.w)<<16);
      o.z = (unsigned)f2bu(vb.x) | ((unsigned)f2bu(vb.y)<<16);
      o.w = (unsigned)f2bu(vb.z) | ((unsigned)f2bu(vb.w)<<16);
      *(uint4*)&afrag[buf][px_g*72 + h*32 + coff_g] = o;
    }
  };

  const int klo = (lane>>4)<<3;         // k-slice within a 32-k chunk
  GATHER(0, 0);
  for(int ph=0; ph<36; ph++){
    __syncthreads();
    if(ph+1 < 36) GATHER(ph+1, (ph+1)&1);
    const unsigned short* ab = afrag[ph&1];
    __builtin_amdgcn_s_setprio(1);      // T5: favor MFMA waves over co-resident gather waves
    #pragma unroll
    for(int h=0; h<2; h++){
      int kt = (ph>>2)*8 + (ph&3)*2 + h;
      short8 aF[4];
      #pragma unroll
      for(int mf=0; mf<4; mf++)
        aF[mf] = *(const short8*)&ab[(mf*16 + (lane&15))*72 + h*32 + klo];
      const unsigned short* wb = w4f + (size_t)kt*8192 + klo;
      #pragma unroll
      for(int nf=0; nf<4; nf++){
        int oc = wave*64 + nf*16 + (lane&15);
        short8 bF = *(const short8*)&wb[oc*32];
        #pragma unroll
        for(int mf=0; mf<4; mf++)
          acc[mf][nf] = __builtin_amdgcn_mfma_f32_16x16x32_bf16(aF[mf], bF, acc[mf][nf], 0,0,0);
      }
    }
    __builtin_amdgcn_s_setprio(0);
  }
  int row0 = ((lane>>4)<<2);
  int col  = lane&15;
  #pragma unroll
  for(int mf=0; mf<4; mf++)
    #pragma unroll
    for(int nf=0; nf<4; nf++){
      int oc = wave*64 + nf*16 + col;
      size_t ob = (size_t)(b*256+oc)*NP2 + ij0 + mf*16 + row0;
      *(f32x4*)(out + ob) = acc[mf][nf];
    }
}

extern "C" void kernel_launch(void* const* d_in, const int* in_sizes, int n_in,
                              void* d_out, int out_size, void* d_ws, size_t ws_size,
                              hipStream_t stream){
  (void)in_sizes; (void)n_in;
  const float* x    = (const float*)d_in[0];
  const float* w1   = (const float*)d_in[1];
  const float* b1   = (const float*)d_in[2];
  const float* g1   = (const float*)d_in[3];
  const float* be1  = (const float*)d_in[4];
  const float* w2   = (const float*)d_in[5];
  const float* b2   = (const float*)d_in[6];
  const float* g2   = (const float*)d_in[7];
  const float* be2  = (const float*)d_in[8];
  const float* woff = (const float*)d_in[9];
  const float* boff = (const float*)d_in[10];
  const float* w4   = (const float*)d_in[11];
  float* out = (float*)d_out;
  float* ws = (float*)d_ws;

  if(ws_size < WS_NEED_BYTES){
    hipMemsetAsync(d_out, 0, (size_t)out_size*sizeof(float), stream);
    return;
  }

  float* sum1   = ws + S_SUM1;
  float* sum2   = ws + S_SUM2;
  float* woff2  = ws + S_WOFF2;
  unsigned short* w4f   = (unsigned short*)(ws + S_W4F);
  unsigned short* w2fh  = (unsigned short*)(ws + S_W2FH);
  unsigned short* w2fl  = (unsigned short*)(ws + S_W2FL);
  unsigned short* woffh = (unsigned short*)(ws + S_WOFFH);
  unsigned short* woffl = (unsigned short*)(ws + S_WOFFL);
  float* offb   = ws + S_OFFB;
  float* ppad   = ws + S_PPAD;
  float* pb1    = ws + S_PPAD;          // convoff split-1 partial (ppad dead by then)
  float* pb2    = ws + S_PB2;           // convoff split-2 partial
  unsigned short* phi = (unsigned short*)(ws + S_PHI);
  unsigned short* plo = (unsigned short*)(ws + S_PLO);
  float* hpad   = ws + S_HPAD;
  unsigned short* hpadh = (unsigned short*)(ws + S_HPADH);
  unsigned short* hpadl = (unsigned short*)(ws + S_HPADL);

  hipMemsetAsync(sum1, 0, 640*sizeof(float), stream);   // sum1(128) + sum2(512)
  k_conv1pool    <<<392,   256, 0, stream>>>(x, w1, b1, ppad, sum1,
                                             w4, woff, w2, w4f, woff2, woffh, woffl,
                                             w2fh, w2fl);
  k_affine1t     <<<408,   256, 0, stream>>>(ppad, sum1, g1, be1, phi, plo);
  k_conv2        <<<392,   256, 0, stream>>>(phi, plo, w2fh, w2fl, b2, hpad, sum2);
  k_affine2      <<<6498,  256, 0, stream>>>(hpad, sum2, g2, be2, hpadh, hpadl);
  k_convoff_mfma <<<1176,  256, 0, stream>>>(hpadh, hpadl, woffh, woffl, offb, pb1, pb2);
  k_offpost      <<<768,   256, 0, stream>>>(offb, pb1, pb2, boff, hpad, woff2);
  k_deform       <<<392,   256, 0, stream>>>(hpadh, offb, w4f, out);
}

// Round 15
// 348.056 us; speedup vs baseline: 1.0407x; 1.0407x over previous
//
#include <hip/hip_runtime.h>
#include <hip/hip_bf16.h>

#define NP1 50176      // 224*224
#define NP2 12544      // 112*112
#define NPP 12996      // 114*114 zero-padded map

typedef __attribute__((ext_vector_type(8))) short short8;   // 8 bf16 = 4 VGPRs
typedef __attribute__((ext_vector_type(4))) float f32x4;

__device__ __forceinline__ unsigned short f2bu(float f){
  __hip_bfloat16 h = __float2bfloat16(f);
  return *reinterpret_cast<unsigned short*>(&h);
}
__device__ __forceinline__ float blo(unsigned u){ union{unsigned q; float f;} x; x.q = u<<16; return x.f; }
__device__ __forceinline__ float bhi(unsigned u){ union{unsigned q; float f;} x; x.q = u & 0xffff0000u; return x.f; }

// ---- workspace layout (float slots) ----
#define S_SUM1   0          // 128
#define S_SUM2   128        // 512
#define S_WOFF2  1280       // 73728 fp32 (k = n*256+c, oc padded 32)
#define S_W4F    75008      // 294912 (589824 bf16 frag-ready)
#define S_W2FH   369920     // 73728 (147456 bf16: w2 hi, frag-ready [kt][oc][kk], k=n*64+c)
#define S_W2FL   443648     // 73728 (147456 bf16: w2 lo)
#define S_OFFB   517376     // 451584 fp32 (NCHW; interior = convoff split-0 PARTIAL, band = exact)
#define S_PPAD   968960     // 1663488 fp32 (NCHW padded, raw pool; DEAD after k_affine1t -> convoff split-1 partial)
#define S_PHI    2632448    // 831744 (1663488 bf16 NHWC hi)
#define S_PLO    3464192    // 831744 (1663488 bf16 NHWC lo)
#define S_HPAD   4295936    // 6653952 fp32 (NHWC padded; post-affine values only on border band)
#define S_HPADL  10949888   // 3326976 (6653952 bf16 NHWC lo)
#define S_WOFFH  14276864   // 36864 (73728 bf16 frag-ready hi)
#define S_WOFFL  14313728   // 36864 (73728 bf16 frag-ready lo)
#define S_PB2    14350592   // 451584 fp32 (convoff split-2 partial)
#define S_HPADH  15014144   // 3326976 (6653952 bf16 NHWC hi)
#define WS_NEED_FLOATS 18341120ull
#define WS_NEED_BYTES  (WS_NEED_FLOATS*4ull)   // 73.4 MB

// ---- conv1+bias+ReLU + 2x2 avgpool (16 oc/block) with fused weight-prep prologue ----
__global__ __launch_bounds__(256) void k_conv1pool(
    const float* __restrict__ x, const float* __restrict__ w1, const float* __restrict__ b1,
    float* __restrict__ ppad, float* __restrict__ sum1,
    const float* __restrict__ w4, const float* __restrict__ woff, const float* __restrict__ w2,
    unsigned short* __restrict__ w4f, float* __restrict__ woff2,
    unsigned short* __restrict__ woffh, unsigned short* __restrict__ woffl,
    unsigned short* __restrict__ w2fh, unsigned short* __restrict__ w2fl){
  // ---- prologue: grid-stride over 884736 weight-prep jobs ----
  for(int t0 = blockIdx.x*256+threadIdx.x; t0 < 884736; t0 += 392*256){
    if(t0 < 589824){
      int kt = t0/8192; int r = t0 - kt*8192;
      int oc = r>>5, kk = r&31;
      int k = kt*32 + kk; int n = k>>8, c = k&255;
      w4f[t0] = f2bu(w4[oc*2304 + c*9 + n]);
    } else if(t0 < 663552){
      int i2 = t0 - 589824;                    // 73728
      int k = i2>>5, oc = i2&31;
      int n = k>>8, c = k&255;
      woff2[i2] = (oc<18) ? woff[oc*2304 + c*9 + n] : 0.f;
    } else if(t0 < 737280){
      int i3 = t0 - 663552;                    // 73728
      int kt = i3>>10; int r = i3 & 1023;
      int oc = r>>5, kk = r&31;
      int k = kt*32 + kk; int n = k>>8, c = k&255;
      float wv = (oc<18) ? woff[oc*2304 + c*9 + n] : 0.f;
      unsigned short hi = f2bu(wv);
      woffh[i3] = hi;
      woffl[i3] = f2bu(wv - blo(hi));
    } else {
      int i4 = t0 - 737280;                    // 147456
      int kt = i4/8192; int r = i4 - kt*8192;
      int oc = r>>5, kk = r&31;
      int k = kt*32 + kk; int n = k>>6, c = k&63;
      float wv = w2[oc*576 + c*9 + n];
      unsigned short hi = f2bu(wv);
      w2fh[i4] = hi;
      w2fl[i4] = f2bu(wv - blo(hi));
    }
  }
  // ---- main: conv1 + pool (bit-identical) ----
  __shared__ float xs[3*34*34];         // 13872 B
  __shared__ float ws[16*28];           // 16 oc x 27 taps (stride 28)
  __shared__ float wbia[16];
  __shared__ float red[4][32];          // [wave][stat*16+o]
  int bid = blockIdx.x;                 // 392
  int tile = bid % 49; int ocg = (bid/49) & 3; int b = bid/(49*4);
  int oc0 = ocg*16;
  int tu = tile/7, tv = tile - 7*(tile/7);
  int tid = threadIdx.x;
  int in0 = tu*32 - 1, jn0 = tv*32 - 1;
  for(int t=tid; t<3468; t+=256){
    int c = t/1156; int r2 = t - c*1156; int rr = r2/34; int cc = r2 - rr*34;
    int ii = in0+rr, jj = jn0+cc;
    xs[t] = (ii>=0 && ii<224 && jj>=0 && jj<224) ? x[(size_t)(b*3+c)*NP1 + ii*224+jj] : 0.f;
  }
  for(int t=tid; t<432; t+=256){
    int o = t/27, q = t - o*27;
    ws[o*28+q] = w1[(oc0+o)*27+q];
  }
  if(tid<16) wbia[tid] = b1[oc0+tid];
  __syncthreads();
  int u = tid>>4, v = tid&15;           // pooled coords in tile
  float xw[3][4][4];
  #pragma unroll
  for(int c=0;c<3;c++)
    #pragma unroll
    for(int r=0;r<4;r++)
      #pragma unroll
      for(int cc=0;cc<4;cc++)
        xw[c][r][cc] = xs[c*1156 + (2*u+r)*34 + (2*v+cc)];
  float s1o[16], s2o[16];
  int U = tu*16+u, V = tv*16+v;
  size_t prow = (size_t)(U+1)*114 + (V+1);
  #pragma unroll 1
  for(int o=0;o<16;o++){
    float w27[27];
    #pragma unroll
    for(int q=0;q<27;q++) w27[q] = ws[o*28+q];
    float bia = wbia[o];
    float pl=0.f, s1=0.f, s2=0.f;
    #pragma unroll
    for(int dy=0;dy<2;dy++){
      #pragma unroll
      for(int dx=0;dx<2;dx++){
        float acc = bia;
        #pragma unroll
        for(int c=0;c<3;c++)
          #pragma unroll
          for(int kh=0;kh<3;kh++)
            #pragma unroll
            for(int kw=0;kw<3;kw++)
              acc += xw[c][dy+kh][dx+kw] * w27[c*9+kh*3+kw];
        acc = fmaxf(acc, 0.f);          // relu BEFORE BN
        pl += acc; s1 += acc; s2 += acc*acc;
      }
    }
    ppad[(size_t)(b*64+oc0+o)*NPP + prow] = 0.25f*pl;
    s1o[o] = s1; s2o[o] = s2;
  }
  const int lane = tid&63, wv = tid>>6;
  #pragma unroll 1
  for(int o=0;o<16;o++){
    float a = s1o[o], c2 = s2o[o];
    #pragma unroll
    for(int off=32; off; off>>=1){
      a  += __shfl_down(a,  off, 64);
      c2 += __shfl_down(c2, off, 64);
    }
    if(lane==0){ red[wv][o] = a; red[wv][16+o] = c2; }
  }
  __syncthreads();
  if(tid<32){
    int o = tid&15, st = tid>>4;
    float v4 = ((red[0][st*16+o] + red[1][st*16+o]) + red[2][st*16+o]) + red[3][st*16+o];
    atomicAdd(&sum1[st*64 + oc0 + o], v4);
  }
}

// ---- BN1 stats (per-block, redundant) + affine + NCHW->NHWC + hi/lo bf16; zero border ----
__global__ __launch_bounds__(256) void k_affine1t(const float* __restrict__ ppad,
        const float* __restrict__ sum1, const float* __restrict__ g1,
        const float* __restrict__ be1,
        unsigned short* __restrict__ phi, unsigned short* __restrict__ plo){
  __shared__ float ls[64*65];
  __shared__ float sc_l[64], sh_l[64];
  int bid = blockIdx.x;                 // 408 = 2*204
  int b = bid/204; int pp0 = (bid - b*204)*64;
  int tid = threadIdx.x;
  if(tid < 64){                         // bit-identical to old k_fin1
    float n = 2.f*(float)NP1;
    float mean = sum1[tid]/n;
    float var  = sum1[64+tid]/n - mean*mean;
    float sc = g1[tid]/sqrtf(var + 1e-5f);
    sc_l[tid] = sc;
    sh_l[tid] = be1[tid] - mean*sc;
  }
  __syncthreads();
  #pragma unroll
  for(int it=0; it<16; it++){
    int t = it*256 + tid;
    int c = t>>6, q = t&63;
    int pp = pp0 + q;
    float v = 0.f;
    if(pp < NPP){
      int row = pp/114, col = pp - row*114;
      if(row>=1 && row<=112 && col>=1 && col<=112)
        v = sc_l[c]*ppad[(size_t)(b*64+c)*NPP + pp] + sh_l[c];
    }
    ls[c*65+q] = v;
  }
  __syncthreads();
  #pragma unroll
  for(int it=0; it<8; it++){            // 2 channels per thread -> packed 4B stores
    int t = it*256 + tid;               // 2048 slots = 64 qloc x 32 cpair
    int qloc = t >> 5; int cp = (t & 31) * 2;
    int pp = pp0 + qloc;
    if(pp < NPP){
      float v0 = ls[cp*65 + qloc], v1 = ls[(cp+1)*65 + qloc];
      unsigned short h0 = f2bu(v0), h1 = f2bu(v1);
      unsigned oh = (unsigned)h0 | ((unsigned)h1<<16);
      unsigned ol = (unsigned)f2bu(v0 - blo(h0)) | ((unsigned)f2bu(v1 - blo(h1))<<16);
      *(unsigned*)&phi[((size_t)b*NPP + pp)*64 + cp] = oh;
      *(unsigned*)&plo[((size_t)b*NPP + pp)*64 + cp] = ol;
    }
  }
}

// ---- conv2: MFMA bf16x2, M-tile 64, N=256, K=576; BN2 partial stats fused in epilogue ----
__global__ __launch_bounds__(256) void k_conv2(
    const unsigned short* __restrict__ phi, const unsigned short* __restrict__ plo,
    const unsigned short* __restrict__ w2fh, const unsigned short* __restrict__ w2fl,
    const float* __restrict__ b2, float* __restrict__ hpad, float* __restrict__ sum2){
  __shared__ float smemf[8800];   // pp_tbl[576 ints] | af(5120 floats) ∪ tb(8224 floats)
  int*  pp_tbl = (int*)smemf;
  unsigned short* afh0 = (unsigned short*)(smemf + 576);    // 2*64*40 shorts = 2560 floats
  unsigned short* afl0 = (unsigned short*)(smemf + 576 + 2560);
  float* tb = smemf + 576;
  const int tid = threadIdx.x;
  const int wave = tid>>6, lane = tid&63;
  const int sidx = (blockIdx.x & 7)*49 + (blockIdx.x >> 3);  // XCD swizzle, grid 392
  const int pix0 = sidx*64;
  const int b = pix0/NP2, ij0 = pix0 - b*NP2;

  for(int t=tid; t<576; t+=256){
    int p = t/9, n = t - 9*(t/9);
    int ij = ij0+p; int i = ij/112, j = ij - i*112;
    pp_tbl[p*9+n] = (i + n/3)*114 + (j + n%3);
  }
  const int px_g = tid>>2;
  const int coff = (tid&3)*8;
  const unsigned short* ph_b = phi + (size_t)b*NPP*64;
  const unsigned short* pl_b = plo + (size_t)b*NPP*64;

  f32x4 acc[4][4] = {};
  __syncthreads();

  auto STAGE = [&](int kt, int buf){
    int n = kt>>1; int cb = ((kt&1)<<5) + coff;
    int pp = pp_tbl[px_g*9 + n];
    *(uint4*)&afh0[buf*2560 + px_g*40 + coff] = *(const uint4*)(ph_b + (size_t)pp*64 + cb);
    *(uint4*)&afl0[buf*2560 + px_g*40 + coff] = *(const uint4*)(pl_b + (size_t)pp*64 + cb);
  };

  const int klo = (lane>>4)<<3;
  STAGE(0, 0);
  for(int kt=0; kt<18; kt++){
    __syncthreads();
    if(kt+1 < 18) STAGE(kt+1, (kt+1)&1);
    const unsigned short* abh = afh0 + (kt&1)*2560;
    const unsigned short* abl = afl0 + (kt&1)*2560;
    short8 aH[4], aL[4];
    #pragma unroll
    for(int mf=0; mf<4; mf++){
      aH[mf] = *(const short8*)&abh[(mf*16 + (lane&15))*40 + klo];
      aL[mf] = *(const short8*)&abl[(mf*16 + (lane&15))*40 + klo];
    }
    #pragma unroll
    for(int nf=0; nf<4; nf++){
      int oc = wave*64 + nf*16 + (lane&15);
      short8 bH = *(const short8*)&w2fh[(size_t)kt*8192 + oc*32 + klo];
      short8 bL = *(const short8*)&w2fl[(size_t)kt*8192 + oc*32 + klo];
      #pragma unroll
      for(int mf=0; mf<4; mf++){
        acc[mf][nf] = __builtin_amdgcn_mfma_f32_16x16x32_bf16(aH[mf], bH, acc[mf][nf], 0,0,0);
        acc[mf][nf] = __builtin_amdgcn_mfma_f32_16x16x32_bf16(aH[mf], bL, acc[mf][nf], 0,0,0);
        acc[mf][nf] = __builtin_amdgcn_mfma_f32_16x16x32_bf16(aL[mf], bH, acc[mf][nf], 0,0,0);
      }
    }
  }
  // epilogue: two 32-px halves through tb (bias+relu), NHWC float4 stores + BN2 partials
  const int row0 = (lane>>4)<<2, col = lane&15;
  float s1q[4] = {0.f,0.f,0.f,0.f}, s2q[4] = {0.f,0.f,0.f,0.f};
  for(int half=0; half<2; half++){
    __syncthreads();
    #pragma unroll
    for(int m2=0; m2<2; m2++){
      int mf = half*2 + m2;
      #pragma unroll
      for(int nf=0; nf<4; nf++){
        int oc = wave*64 + nf*16 + col;
        #pragma unroll
        for(int r=0;r<4;r++) tb[(m2*16 + row0 + r)*257 + oc] = acc[mf][nf][r];
      }
    }
    __syncthreads();
    #pragma unroll
    for(int it=0; it<8; it++){
      int id = it*256 + tid;
      int pxl = id>>6, oc4 = id&63;            // oc4 == tid&63 (constant per thread)
      int px = half*32 + pxl;
      int ij = ij0+px; int i = ij/112, j = ij - i*112;
      int pp = (i+1)*114 + (j+1);
      float4 v;
      v.x = fmaxf(tb[pxl*257 + oc4*4+0] + b2[oc4*4+0], 0.f);
      v.y = fmaxf(tb[pxl*257 + oc4*4+1] + b2[oc4*4+1], 0.f);
      v.z = fmaxf(tb[pxl*257 + oc4*4+2] + b2[oc4*4+2], 0.f);
      v.w = fmaxf(tb[pxl*257 + oc4*4+3] + b2[oc4*4+3], 0.f);
      *(float4*)&hpad[((size_t)b*NPP + pp)*256 + oc4*4] = v;   // raw (pre-BN2)
      s1q[0] += v.x; s2q[0] += v.x*v.x;
      s1q[1] += v.y; s2q[1] += v.y*v.y;
      s1q[2] += v.z; s2q[2] += v.z*v.z;
      s1q[3] += v.w; s2q[3] += v.w*v.w;
    }
  }
  // block-level BN2 partial reduce through tb, one atomic pair per oc
  __syncthreads();
  #pragma unroll
  for(int q=0;q<4;q++){ tb[tid*4+q] = s1q[q]; tb[1024 + tid*4+q] = s2q[q]; }
  __syncthreads();
  {
    int oc = tid;                               // 256 ocs
    float s1 = ((tb[oc] + tb[256+oc]) + tb[512+oc]) + tb[768+oc];
    float s2 = ((tb[1024+oc] + tb[1280+oc]) + tb[1536+oc]) + tb[1792+oc];
    atomicAdd(&sum2[oc], s1); atomicAdd(&sum2[256+oc], s2);
  }
}

// ---- BN2 stats (per-block, redundant) + affine, 4-ch vectorized; bf16 hi/lo; band fp32 ----
__global__ __launch_bounds__(256) void k_affine2(float* __restrict__ hpad,
                          const float* __restrict__ sum2, const float* __restrict__ g2,
                          const float* __restrict__ be2,
                          unsigned short* __restrict__ hpadh, unsigned short* __restrict__ hpadl){
  __shared__ float sc_l[256], sh_l[256];
  int tid = threadIdx.x;
  {                                     // bit-identical to old k_fin2
    float n = 2.f*(float)NP2;
    float mean = sum2[tid]/n;
    float var  = sum2[256+tid]/n - mean*mean;
    float sc = g2[tid]/sqrtf(var + 1e-5f);
    sc_l[tid] = sc;
    sh_l[tid] = be2[tid] - mean*sc;
  }
  __syncthreads();
  int idx = blockIdx.x*256+tid;            // 1663488 = 6498*256
  int c4 = (idx & 63) << 2;                // 0,4,..252
  int pi = idx >> 6;                       // 0..25991
  int pp = pi % NPP;
  int row = pp/114, col = pp - row*114;
  bool in = (row>=1 && row<=112 && col>=1 && col<=112);
  float4 h = *(const float4*)&hpad[(size_t)pi*256 + c4];
  float4 v;
  v.x = in ? (sc_l[c4+0]*h.x + sh_l[c4+0]) : 0.f;
  v.y = in ? (sc_l[c4+1]*h.y + sh_l[c4+1]) : 0.f;
  v.z = in ? (sc_l[c4+2]*h.z + sh_l[c4+2]) : 0.f;
  v.w = in ? (sc_l[c4+3]*h.w + sh_l[c4+3]) : 0.f;
  // fp32 hpad is only consumed by k_offfix on the border band
  bool band = (row<6) || (row>107) || (col<6) || (col>107);
  if(band) *(float4*)&hpad[(size_t)pi*256 + c4] = v;
  unsigned short hx = f2bu(v.x), hy = f2bu(v.y), hz = f2bu(v.z), hw = f2bu(v.w);
  uint2 oh, ol;
  oh.x = (unsigned)hx | ((unsigned)hy<<16);
  oh.y = (unsigned)hz | ((unsigned)hw<<16);
  ol.x = (unsigned)f2bu(v.x - blo(hx)) | ((unsigned)f2bu(v.y - blo(hy))<<16);
  ol.y = (unsigned)f2bu(v.z - blo(hz)) | ((unsigned)f2bu(v.w - blo(hw))<<16);
  *(uint2*)&hpadh[(size_t)pi*256 + c4] = oh;
  *(uint2*)&hpadl[(size_t)pi*256 + c4] = ol;
}

// ---- offset conv, tap-split-K MFMA: 3 splits x 3 taps, grid 1176 = 8 xcd * 147 ----
__global__ __launch_bounds__(256) void k_convoff_mfma(
    const unsigned short* __restrict__ hpadh, const unsigned short* __restrict__ hpadl,
    const unsigned short* __restrict__ woffh, const unsigned short* __restrict__ woffl,
    float* __restrict__ p0, float* __restrict__ p1, float* __restrict__ p2){
  __shared__ int pp_tbl[192];                              // 64 px x 3 taps
  __shared__ __align__(16) unsigned short afh[2][64*72];   // 18432 B
  __shared__ __align__(16) unsigned short afl[2][64*72];   // 18432 B
  const int tid = threadIdx.x;
  const int wave = tid>>6, lane = tid&63;
  const int g = blockIdx.x;
  const int xcd = g & 7;
  const int rr  = g >> 3;               // 0..146
  const int split = rr % 3;             // k-split: taps split*3 .. +2
  const int sstrip = rr / 3;            // 0..48
  const int strip = xcd*49 + sstrip;    // 0..391
  const int pix0 = strip*64;
  const int b = pix0/NP2, ij0 = pix0 - b*NP2;
  const int n0 = split*3;

  for(int t=tid; t<192; t+=256){
    int p = t/3, nl = t - 3*(t/3);
    int ij = ij0+p; int i = ij/112, j = ij - i*112;
    int n = n0 + nl;
    pp_tbl[p*3+nl] = (i + n/3)*114 + (j + n%3);
  }
  const int px_g = tid>>2;              // 64 px, 4 thr/px
  const int coff = (tid&3)*16;          // 16-short (32B) slice of the 64-k phase
  const unsigned short* ph_b = hpadh + (size_t)b*NPP*256;
  const unsigned short* pl_b = hpadl + (size_t)b*NPP*256;
  const int r15 = lane&15, klo = (lane>>4)<<3;

  f32x4 acc[2] = {};
  __syncthreads();                      // pp_tbl ready

  auto STAGE = [&](int ph, int buf){    // ph = nl*4 + q : stages k = q*64..+63 of tap n0+nl
    int nl = ph>>2, q = ph&3;
    int pp = pp_tbl[px_g*3 + nl];
    int cb = q*64 + coff;
    uint4 h0 = *(const uint4*)(ph_b + (size_t)pp*256 + cb);
    uint4 h1 = *(const uint4*)(ph_b + (size_t)pp*256 + cb + 8);
    uint4 l0 = *(const uint4*)(pl_b + (size_t)pp*256 + cb);
    uint4 l1 = *(const uint4*)(pl_b + (size_t)pp*256 + cb + 8);
    *(uint4*)&afh[buf][px_g*72 + coff    ] = h0;
    *(uint4*)&afh[buf][px_g*72 + coff + 8] = h1;
    *(uint4*)&afl[buf][px_g*72 + coff    ] = l0;
    *(uint4*)&afl[buf][px_g*72 + coff + 8] = l1;
  };

  STAGE(0, 0);
  for(int ph=0; ph<12; ph++){
    __syncthreads();
    if(ph+1 < 12) STAGE(ph+1, (ph+1)&1);
    const unsigned short* ah = &afh[ph&1][(wave*16 + r15)*72];
    const unsigned short* al = &afl[ph&1][(wave*16 + r15)*72];
    const int n = n0 + (ph>>2), q = ph&3;
    #pragma unroll
    for(int half=0; half<2; half++){
      int kt = n*8 + q*2 + half;        // global k-tile index (B layout unchanged)
      short8 aH = *(const short8*)&ah[half*32 + klo];
      short8 aL = *(const short8*)&al[half*32 + klo];
      #pragma unroll
      for(int nf=0; nf<2; nf++){
        int oc = nf*16 + r15;
        short8 bH = *(const short8*)&woffh[(size_t)kt*1024 + oc*32 + klo];
        short8 bL = *(const short8*)&woffl[(size_t)kt*1024 + oc*32 + klo];
        acc[nf] = __builtin_amdgcn_mfma_f32_16x16x32_bf16(aH, bH, acc[nf], 0,0,0);
        acc[nf] = __builtin_amdgcn_mfma_f32_16x16x32_bf16(aH, bL, acc[nf], 0,0,0);
        acc[nf] = __builtin_amdgcn_mfma_f32_16x16x32_bf16(aL, bH, acc[nf], 0,0,0);
      }
    }
  }
  float* dst = (split==0) ? p0 : (split==1) ? p1 : p2;
  const int row0 = (lane>>4)<<2;
  #pragma unroll
  for(int nf=0; nf<2; nf++){
    int oc = nf*16 + r15;
    if(oc < 18)
      *(f32x4*)(dst + (size_t)(b*18+oc)*NP2 + ij0 + wave*16 + row0) = acc[nf];
  }
}

// ---- exact-fp32 recompute of offsets on the 3-wide border band (grid 327) ----
// Interior offb is left as the split-0 partial; k_deform combines partials inline.
__global__ __launch_bounds__(256) void k_offfix(const float* __restrict__ hpad,
        const float* __restrict__ woff2, const float* __restrict__ boff,
        float* __restrict__ offb){
  int idx = blockIdx.x*256 + threadIdx.x;   // 327*256 = 83712 = 2*1308*32
  if(idx >= 83712) return;
  int oc = idx & 31;
  int pid = idx >> 5;                       // 0..2615
  int b = pid / 1308; int t = pid - b*1308;
  int i, j;
  if(t < 672){                              // full rows 0,1,2,109,110,111
    int r = t/112; i = (r<3) ? r : 106+r; j = t - (t/112)*112;
  } else {                                  // cols 0,1,2,109,110,111 of rows 3..108
    int u = t - 672; i = 3 + u/6; int c6 = u - 6*(u/6);
    j = (c6<3) ? c6 : 106+c6;
  }
  const float* hb = hpad + (size_t)b*NPP*256;
  float a0=0.f, a1=0.f, a2=0.f, a3=0.f;     // 4 independent chains
  for(int n=0;n<9;n++){
    const float* ap = hb + (size_t)((i + n/3)*114 + (j + n%3))*256;
    const float* wp = woff2 + (size_t)n*256*32 + oc;
    #pragma unroll 4
    for(int c=0;c<256;c+=4){
      float4 a = *(const float4*)(ap + c);
      a0 = fmaf(a.x, wp[(c+0)*32], a0);
      a1 = fmaf(a.y, wp[(c+1)*32], a1);
      a2 = fmaf(a.z, wp[(c+2)*32], a2);
      a3 = fmaf(a.w, wp[(c+3)*32], a3);
    }
  }
  if(oc < 18)
    offb[(size_t)(b*18+oc)*NP2 + i*112 + j] = ((a0+a1)+(a2+a3)) + boff[oc];
}

// ---- deformable conv: MFMA bf16, M-tile 64, 36 merged phases (k=64 each), grid 392 ----
// Prologue combines the 3 convoff k-split partials inline for interior pixels
// (same ((p0+p1)+p2)+bias order as the deleted reduce kernel -> bit-identical);
// band pixels read the exact-fp32 offb written by k_offfix.
__global__ __launch_bounds__(256) void k_deform(
    const unsigned short* __restrict__ hpadh,       // NHWC bf16, affine'd, zero border
    const float* __restrict__ offb,                 // split-0 partial (interior) / exact (band)
    const float* __restrict__ p1, const float* __restrict__ p2,
    const float* __restrict__ boff,
    const unsigned short* __restrict__ w4f,         // frag-ready bf16 [72][256][32]
    float* __restrict__ out){
  __shared__ int   gidx[64][9][4];
  __shared__ float gwt [64][9][4];
  __shared__ __align__(16) unsigned short afrag[2][64*72];  // px stride 72 shorts (bank-safe)
  const int tid = threadIdx.x;
  const int wave = tid>>6, lane = tid&63;
  const int sidx = (blockIdx.x & 7)*49 + (blockIdx.x >> 3);
  const int pix0 = sidx*64;
  const int b = pix0/NP2, ij0 = pix0 - b*NP2;

  for(int t=tid; t<576; t+=256){
    int p = t/9, n = t - 9*(t/9);
    int ij = ij0+p; int i = ij/112, j = ij - i*112;
    size_t bx = (size_t)(b*18 + 2*n  )*NP2 + ij;
    size_t by = (size_t)(b*18 + 2*n+1)*NP2 + ij;
    bool band = (i<3) || (i>108) || (j<3) || (j>108);
    float ox, oy;
    if(band){                           // exact values from k_offfix
      ox = offb[bx]; oy = offb[by];
    } else {                            // inline 3-split combine (same order as old reduce)
      ox = ((offb[bx] + p1[bx]) + p2[bx]) + boff[2*n];
      oy = ((offb[by] + p1[by]) + p2[by]) + boff[2*n+1];
    }
    float px = (float)(i + n/3) + ox;
    float py = (float)(j + n%3) + oy;
    float fpx = floorf(px), fpy = floorf(py);
    float qltxf = fminf(fmaxf(fpx,     0.f),113.f);
    float qltyf = fminf(fmaxf(fpy,     0.f),113.f);
    float qrbxf = fminf(fmaxf(fpx+1.f, 0.f),113.f);
    float qrbyf = fminf(fmaxf(fpy+1.f, 0.f),113.f);
    int qltx=(int)qltxf, qlty=(int)qltyf, qrbx=(int)qrbxf, qrby=(int)qrbyf;
    bool mx = (px<1.f)||(px>112.f);
    bool my = (py<1.f)||(py>112.f);
    float pxc = fminf(fmaxf(mx?fpx:px, 0.f),113.f);
    float pyc = fminf(fmaxf(my?fpy:py, 0.f),113.f);
    float glt = (1.f+(qltxf-pxc))*(1.f+(qltyf-pyc));
    float grb = (1.f-(qrbxf-pxc))*(1.f-(qrbyf-pyc));
    float glb = (1.f+(qltxf-pxc))*(1.f-(qrbyf-pyc));
    float grt = (1.f-(qrbxf-pxc))*(1.f+(qltyf-pyc));
    gidx[p][n][0]=qltx*114+qlty; gwt[p][n][0]=glt;
    gidx[p][n][1]=qrbx*114+qrby; gwt[p][n][1]=grb;
    gidx[p][n][2]=qltx*114+qrby; gwt[p][n][2]=glb;  // (lt_x, rb_y)
    gidx[p][n][3]=qrbx*114+qlty; gwt[p][n][3]=grt;  // (rb_x, lt_y)
  }

  const int px_g   = tid>>2;            // 0..63
  const int coff_g = (tid&3)*8;         // 8-channel slice within each 32-ch k-chunk
  const unsigned short* hb = hpadh + (size_t)b*NPP*256;

  f32x4 acc[4][4] = {};
  __syncthreads();

  // phase ph covers tap n = ph>>2, channels (ph&3)*64 .. +63
  auto GATHER = [&](int ph, int buf){
    int n = ph>>2; int qb = (ph&3)<<6;
    const int*   gi = gidx[px_g][n];
    const float* gw = gwt[px_g][n];
    int i0 = gi[0], i1 = gi[1], i2 = gi[2], i3 = gi[3];
    float w0 = gw[0], w1 = gw[1], w2 = gw[2], w3 = gw[3];
    #pragma unroll
    for(int h=0; h<2; h++){
      int cb = qb + h*32 + coff_g;
      f32x4 va = {0.f,0.f,0.f,0.f}, vb = {0.f,0.f,0.f,0.f};
      const uint4 u0 = *(const uint4*)(hb + (size_t)i0*256 + cb);
      const uint4 u1 = *(const uint4*)(hb + (size_t)i1*256 + cb);
      const uint4 u2 = *(const uint4*)(hb + (size_t)i2*256 + cb);
      const uint4 u3 = *(const uint4*)(hb + (size_t)i3*256 + cb);
      // per-channel corner order 0,1,2,3 — identical to the 32-k version
      va.x = fmaf(w0, blo(u0.x), va.x); va.y = fmaf(w0, bhi(u0.x), va.y);
      va.z = fmaf(w0, blo(u0.y), va.z); va.w = fmaf(w0, bhi(u0.y), va.w);
      vb.x = fmaf(w0, blo(u0.z), vb.x); vb.y = fmaf(w0, bhi(u0.z), vb.y);
      vb.z = fmaf(w0, blo(u0.w), vb.z); vb.w = fmaf(w0, bhi(u0.w), vb.w);
      va.x = fmaf(w1, blo(u1.x), va.x); va.y = fmaf(w1, bhi(u1.x), va.y);
      va.z = fmaf(w1, blo(u1.y), va.z); va.w = fmaf(w1, bhi(u1.y), va.w);
      vb.x = fmaf(w1, blo(u1.z), vb.x); vb.y = fmaf(w1, bhi(u1.z), vb.y);
      vb.z = fmaf(w1, blo(u1.w), vb.z); vb.w = fmaf(w1, bhi(u1.w), vb.w);
      va.x = fmaf(w2, blo(u2.x), va.x); va.y = fmaf(w2, bhi(u2.x), va.y);
      va.z = fmaf(w2, blo(u2.y), va.z); va.w = fmaf(w2, bhi(u2.y), va.w);
      vb.x = fmaf(w2, blo(u2.z), vb.x); vb.y = fmaf(w2, bhi(u2.z), vb.y);
      vb.z = fmaf(w2, blo(u2.w), vb.z); vb.w = fmaf(w2, bhi(u2.w), vb.w);
      va.x = fmaf(w3, blo(u3.x), va.x); va.y = fmaf(w3, bhi(u3.x), va.y);
      va.z = fmaf(w3, blo(u3.y), va.z); va.w = fmaf(w3, bhi(u3.y), va.w);
      vb.x = fmaf(w3, blo(u3.z), vb.x); vb.y = fmaf(w3, bhi(u3.z), vb.y);
      vb.z = fmaf(w3, blo(u3.w), vb.z); vb.w = fmaf(w3, bhi(u3.w), vb.w);
      uint4 o;
      o.x = (unsigned)f2bu(va.x) | ((unsigned)f2bu(va.y)<<16);
      o.y = (unsigned)f2bu(va.z) | ((unsigned)f2bu(va.w)<<16);
      o.z = (unsigned)f2bu(vb.x) | ((unsigned)f2bu(vb.y)<<16);
      o.w = (unsigned)f2bu(vb.z) | ((unsigned)f2bu(vb.w)<<16);
      *(uint4*)&afrag[buf][px_g*72 + h*32 + coff_g] = o;
    }
  };

  const int klo = (lane>>4)<<3;         // k-slice within a 32-k chunk
  GATHER(0, 0);
  for(int ph=0; ph<36; ph++){
    __syncthreads();
    if(ph+1 < 36) GATHER(ph+1, (ph+1)&1);
    const unsigned short* ab = afrag[ph&1];
    #pragma unroll
    for(int h=0; h<2; h++){
      int kt = (ph>>2)*8 + (ph&3)*2 + h;
      short8 aF[4];
      #pragma unroll
      for(int mf=0; mf<4; mf++)
        aF[mf] = *(const short8*)&ab[(mf*16 + (lane&15))*72 + h*32 + klo];
      const unsigned short* wb = w4f + (size_t)kt*8192 + klo;
      #pragma unroll
      for(int nf=0; nf<4; nf++){
        int oc = wave*64 + nf*16 + (lane&15);
        short8 bF = *(const short8*)&wb[oc*32];
        #pragma unroll
        for(int mf=0; mf<4; mf++)
          acc[mf][nf] = __builtin_amdgcn_mfma_f32_16x16x32_bf16(aF[mf], bF, acc[mf][nf], 0,0,0);
      }
    }
  }
  int row0 = ((lane>>4)<<2);
  int col  = lane&15;
  #pragma unroll
  for(int mf=0; mf<4; mf++)
    #pragma unroll
    for(int nf=0; nf<4; nf++){
      int oc = wave*64 + nf*16 + col;
      size_t ob = (size_t)(b*256+oc)*NP2 + ij0 + mf*16 + row0;
      *(f32x4*)(out + ob) = acc[mf][nf];
    }
}

extern "C" void kernel_launch(void* const* d_in, const int* in_sizes, int n_in,
                              void* d_out, int out_size, void* d_ws, size_t ws_size,
                              hipStream_t stream){
  (void)in_sizes; (void)n_in;
  const float* x    = (const float*)d_in[0];
  const float* w1   = (const float*)d_in[1];
  const float* b1   = (const float*)d_in[2];
  const float* g1   = (const float*)d_in[3];
  const float* be1  = (const float*)d_in[4];
  const float* w2   = (const float*)d_in[5];
  const float* b2   = (const float*)d_in[6];
  const float* g2   = (const float*)d_in[7];
  const float* be2  = (const float*)d_in[8];
  const float* woff = (const float*)d_in[9];
  const float* boff = (const float*)d_in[10];
  const float* w4   = (const float*)d_in[11];
  float* out = (float*)d_out;
  float* ws = (float*)d_ws;

  if(ws_size < WS_NEED_BYTES){
    hipMemsetAsync(d_out, 0, (size_t)out_size*sizeof(float), stream);
    return;
  }

  float* sum1   = ws + S_SUM1;
  float* sum2   = ws + S_SUM2;
  float* woff2  = ws + S_WOFF2;
  unsigned short* w4f   = (unsigned short*)(ws + S_W4F);
  unsigned short* w2fh  = (unsigned short*)(ws + S_W2FH);
  unsigned short* w2fl  = (unsigned short*)(ws + S_W2FL);
  unsigned short* woffh = (unsigned short*)(ws + S_WOFFH);
  unsigned short* woffl = (unsigned short*)(ws + S_WOFFL);
  float* offb   = ws + S_OFFB;
  float* ppad   = ws + S_PPAD;
  float* pb1    = ws + S_PPAD;          // convoff split-1 partial (ppad dead by then)
  float* pb2    = ws + S_PB2;           // convoff split-2 partial
  unsigned short* phi = (unsigned short*)(ws + S_PHI);
  unsigned short* plo = (unsigned short*)(ws + S_PLO);
  float* hpad   = ws + S_HPAD;
  unsigned short* hpadh = (unsigned short*)(ws + S_HPADH);
  unsigned short* hpadl = (unsigned short*)(ws + S_HPADL);

  hipMemsetAsync(sum1, 0, 640*sizeof(float), stream);   // sum1(128) + sum2(512)
  k_conv1pool    <<<392,   256, 0, stream>>>(x, w1, b1, ppad, sum1,
                                             w4, woff, w2, w4f, woff2, woffh, woffl,
                                             w2fh, w2fl);
  k_affine1t     <<<408,   256, 0, stream>>>(ppad, sum1, g1, be1, phi, plo);
  k_conv2        <<<392,   256, 0, stream>>>(phi, plo, w2fh, w2fl, b2, hpad, sum2);
  k_affine2      <<<6498,  256, 0, stream>>>(hpad, sum2, g2, be2, hpadh, hpadl);
  k_convoff_mfma <<<1176,  256, 0, stream>>>(hpadh, hpadl, woffh, woffl, offb, pb1, pb2);
  k_offfix       <<<327,   256, 0, stream>>>(hpad, woff2, boff, offb);
  k_deform       <<<392,   256, 0, stream>>>(hpadh, offb, pb1, pb2, boff, w4f, out);
}

// Round 16
// 345.849 us; speedup vs baseline: 1.0474x; 1.0064x over previous
//
#include <hip/hip_runtime.h>
#include <hip/hip_bf16.h>

#define NP1 50176      // 224*224
#define NP2 12544      // 112*112
#define NPP 12996      // 114*114 zero-padded map

typedef __attribute__((ext_vector_type(8))) short short8;   // 8 bf16 = 4 VGPRs
typedef __attribute__((ext_vector_type(4))) float f32x4;

__device__ __forceinline__ unsigned short f2bu(float f){
  __hip_bfloat16 h = __float2bfloat16(f);
  return *reinterpret_cast<unsigned short*>(&h);
}
__device__ __forceinline__ float blo(unsigned u){ union{unsigned q; float f;} x; x.q = u<<16; return x.f; }
__device__ __forceinline__ float bhi(unsigned u){ union{unsigned q; float f;} x; x.q = u & 0xffff0000u; return x.f; }

// ---- workspace layout (float slots) ----
#define S_SUM1   0          // 128
#define S_SUM2   128        // 512
#define S_WOFF2  1280       // 73728 fp32 (k = n*256+c, oc padded 32)
#define S_W4F    75008      // 294912 (589824 bf16 frag-ready)
#define S_W2FH   369920     // 73728 (147456 bf16: w2 hi, frag-ready [kt][oc][kk], k=n*64+c)
#define S_W2FL   443648     // 73728 (147456 bf16: w2 lo)
#define S_OFFB   517376     // 451584 fp32 (NCHW; interior = convoff split-0 PARTIAL, band = exact)
#define S_PPAD   968960     // 1663488 fp32 (pooled NHWC [2][112][112][64]; DEAD after k_affine1t -> convoff split-1 partial)
#define S_PHI    2632448    // 831744 (1663488 bf16 NHWC hi)
#define S_PLO    3464192    // 831744 (1663488 bf16 NHWC lo)
#define S_HPAD   4295936    // 6653952 fp32 (NHWC padded; post-affine values only on border band)
#define S_HPADL  10949888   // 3326976 (6653952 bf16 NHWC lo)
#define S_WOFFH  14276864   // 36864 (73728 bf16 frag-ready hi)
#define S_WOFFL  14313728   // 36864 (73728 bf16 frag-ready lo)
#define S_PB2    14350592   // 451584 fp32 (convoff split-2 partial)
#define S_HPADH  15014144   // 3326976 (6653952 bf16 NHWC hi)
#define WS_NEED_FLOATS 18341120ull
#define WS_NEED_BYTES  (WS_NEED_FLOATS*4ull)   // 73.4 MB

// ---- conv1+bias+ReLU + 2x2 avgpool (16 oc/block), NHWC pooled output,
//      fused weight-prep prologue. grid 392 = 2b * 4ocg * 49tiles. ----
__global__ __launch_bounds__(256) void k_conv1pool(
    const float* __restrict__ x, const float* __restrict__ w1, const float* __restrict__ b1,
    float* __restrict__ pooled, float* __restrict__ sum1,
    const float* __restrict__ w4, const float* __restrict__ woff, const float* __restrict__ w2,
    unsigned short* __restrict__ w4f, float* __restrict__ woff2,
    unsigned short* __restrict__ woffh, unsigned short* __restrict__ woffl,
    unsigned short* __restrict__ w2fh, unsigned short* __restrict__ w2fl){
  // ---- prologue: grid-stride over 884736 weight-prep jobs ----
  for(int t0 = blockIdx.x*256+threadIdx.x; t0 < 884736; t0 += 392*256){
    if(t0 < 589824){
      int kt = t0/8192; int r = t0 - kt*8192;
      int oc = r>>5, kk = r&31;
      int k = kt*32 + kk; int n = k>>8, c = k&255;
      w4f[t0] = f2bu(w4[oc*2304 + c*9 + n]);
    } else if(t0 < 663552){
      int i2 = t0 - 589824;                    // 73728
      int k = i2>>5, oc = i2&31;
      int n = k>>8, c = k&255;
      woff2[i2] = (oc<18) ? woff[oc*2304 + c*9 + n] : 0.f;
    } else if(t0 < 737280){
      int i3 = t0 - 663552;                    // 73728
      int kt = i3>>10; int r = i3 & 1023;
      int oc = r>>5, kk = r&31;
      int k = kt*32 + kk; int n = k>>8, c = k&255;
      float wv = (oc<18) ? woff[oc*2304 + c*9 + n] : 0.f;
      unsigned short hi = f2bu(wv);
      woffh[i3] = hi;
      woffl[i3] = f2bu(wv - blo(hi));
    } else {
      int i4 = t0 - 737280;                    // 147456
      int kt = i4/8192; int r = i4 - kt*8192;
      int oc = r>>5, kk = r&31;
      int k = kt*32 + kk; int n = k>>6, c = k&63;
      float wv = w2[oc*576 + c*9 + n];
      unsigned short hi = f2bu(wv);
      w2fh[i4] = hi;
      w2fl[i4] = f2bu(wv - blo(hi));
    }
  }
  // ---- main: conv1 + pool (values bit-identical; output layout NHWC) ----
  __shared__ float xs[3*34*34];         // 13872 B
  __shared__ float ws[16*28];           // 16 oc x 27 taps (stride 28)
  __shared__ float wbia[16];
  __shared__ float red[4][32];          // [wave][stat*16+o]
  int bid = blockIdx.x;                 // 392
  int tile = bid % 49; int ocg = (bid/49) & 3; int b = bid/(49*4);
  int oc0 = ocg*16;
  int tu = tile/7, tv = tile - 7*(tile/7);
  int tid = threadIdx.x;
  int in0 = tu*32 - 1, jn0 = tv*32 - 1;
  for(int t=tid; t<3468; t+=256){
    int c = t/1156; int r2 = t - c*1156; int rr = r2/34; int cc = r2 - rr*34;
    int ii = in0+rr, jj = jn0+cc;
    xs[t] = (ii>=0 && ii<224 && jj>=0 && jj<224) ? x[(size_t)(b*3+c)*NP1 + ii*224+jj] : 0.f;
  }
  for(int t=tid; t<432; t+=256){
    int o = t/27, q = t - o*27;
    ws[o*28+q] = w1[(oc0+o)*27+q];
  }
  if(tid<16) wbia[tid] = b1[oc0+tid];
  __syncthreads();
  int u = tid>>4, v = tid&15;           // pooled coords in tile
  float xw[3][4][4];
  #pragma unroll
  for(int c=0;c<3;c++)
    #pragma unroll
    for(int r=0;r<4;r++)
      #pragma unroll
      for(int cc=0;cc<4;cc++)
        xw[c][r][cc] = xs[c*1156 + (2*u+r)*34 + (2*v+cc)];
  float s1o[16], s2o[16], pv[16];
  int U = tu*16+u, V = tv*16+v;
  #pragma unroll 1
  for(int o=0;o<16;o++){
    float w27[27];
    #pragma unroll
    for(int q=0;q<27;q++) w27[q] = ws[o*28+q];
    float bia = wbia[o];
    float pl=0.f, s1=0.f, s2=0.f;
    #pragma unroll
    for(int dy=0;dy<2;dy++){
      #pragma unroll
      for(int dx=0;dx<2;dx++){
        float acc = bia;
        #pragma unroll
        for(int c=0;c<3;c++)
          #pragma unroll
          for(int kh=0;kh<3;kh++)
            #pragma unroll
            for(int kw=0;kw<3;kw++)
              acc += xw[c][dy+kh][dx+kw] * w27[c*9+kh*3+kw];
        acc = fmaxf(acc, 0.f);          // relu BEFORE BN
        pl += acc; s1 += acc; s2 += acc*acc;
      }
    }
    pv[o] = 0.25f*pl;
    s1o[o] = s1; s2o[o] = s2;
  }
  // NHWC pooled store: 16 consecutive channels of this px -> 4x float4
  {
    float* dst = pooled + ((size_t)b*NP2 + U*112 + V)*64 + oc0;
    #pragma unroll
    for(int q4=0;q4<4;q4++){
      float4 o4; o4.x=pv[q4*4+0]; o4.y=pv[q4*4+1]; o4.z=pv[q4*4+2]; o4.w=pv[q4*4+3];
      *(float4*)(dst + q4*4) = o4;
    }
  }
  const int lane = tid&63, wv = tid>>6;
  #pragma unroll 1
  for(int o=0;o<16;o++){
    float a = s1o[o], c2 = s2o[o];
    #pragma unroll
    for(int off=32; off; off>>=1){
      a  += __shfl_down(a,  off, 64);
      c2 += __shfl_down(c2, off, 64);
    }
    if(lane==0){ red[wv][o] = a; red[wv][16+o] = c2; }
  }
  __syncthreads();
  if(tid<32){
    int o = tid&15, st = tid>>4;
    float v4 = ((red[0][st*16+o] + red[1][st*16+o]) + red[2][st*16+o]) + red[3][st*16+o];
    atomicAdd(&sum1[st*64 + oc0 + o], v4);
  }
}

// ---- BN1 stats (per-block, redundant) + affine, pure streaming (no LDS transpose);
//      zero border; packed 4B hi/lo stores. grid 3249 = 831744/256. ----
__global__ __launch_bounds__(256) void k_affine1t(const float* __restrict__ pooled,
        const float* __restrict__ sum1, const float* __restrict__ g1,
        const float* __restrict__ be1,
        unsigned short* __restrict__ phi, unsigned short* __restrict__ plo){
  __shared__ float sc_l[64], sh_l[64];
  int tid = threadIdx.x;
  if(tid < 64){                         // bit-identical to old k_fin1
    float n = 2.f*(float)NP1;
    float mean = sum1[tid]/n;
    float var  = sum1[64+tid]/n - mean*mean;
    float sc = g1[tid]/sqrtf(var + 1e-5f);
    sc_l[tid] = sc;
    sh_l[tid] = be1[tid] - mean*sc;
  }
  __syncthreads();
  int idx = blockIdx.x*256 + tid;       // 831744 = 2*NPP*32 channel-pairs
  int cp = (idx & 31) * 2;              // channel pair 0,2,..,62
  int pi = idx >> 5;                    // 0..25991 = b*NPP + pp
  int b  = pi / NPP, pp = pi - b*NPP;
  int row = pp/114, col = pp - row*114;
  float v0 = 0.f, v1 = 0.f;
  if(row>=1 && row<=112 && col>=1 && col<=112){
    const float* src = pooled + ((size_t)b*NP2 + (row-1)*112 + (col-1))*64 + cp;
    v0 = sc_l[cp]*src[0] + sh_l[cp];
    v1 = sc_l[cp+1]*src[1] + sh_l[cp+1];
  }
  unsigned short h0 = f2bu(v0), h1 = f2bu(v1);
  unsigned oh = (unsigned)h0 | ((unsigned)h1<<16);
  unsigned ol = (unsigned)f2bu(v0 - blo(h0)) | ((unsigned)f2bu(v1 - blo(h1))<<16);
  *(unsigned*)&phi[((size_t)b*NPP + pp)*64 + cp] = oh;
  *(unsigned*)&plo[((size_t)b*NPP + pp)*64 + cp] = ol;
}

// ---- conv2: MFMA bf16x2, M-tile 64, N=256, K=576; BN2 partial stats fused in epilogue ----
__global__ __launch_bounds__(256) void k_conv2(
    const unsigned short* __restrict__ phi, const unsigned short* __restrict__ plo,
    const unsigned short* __restrict__ w2fh, const unsigned short* __restrict__ w2fl,
    const float* __restrict__ b2, float* __restrict__ hpad, float* __restrict__ sum2){
  __shared__ float smemf[8800];   // pp_tbl[576 ints] | af(5120 floats) ∪ tb(8224 floats)
  int*  pp_tbl = (int*)smemf;
  unsigned short* afh0 = (unsigned short*)(smemf + 576);    // 2*64*40 shorts = 2560 floats
  unsigned short* afl0 = (unsigned short*)(smemf + 576 + 2560);
  float* tb = smemf + 576;
  const int tid = threadIdx.x;
  const int wave = tid>>6, lane = tid&63;
  const int sidx = (blockIdx.x & 7)*49 + (blockIdx.x >> 3);  // XCD swizzle, grid 392
  const int pix0 = sidx*64;
  const int b = pix0/NP2, ij0 = pix0 - b*NP2;

  for(int t=tid; t<576; t+=256){
    int p = t/9, n = t - 9*(t/9);
    int ij = ij0+p; int i = ij/112, j = ij - i*112;
    pp_tbl[p*9+n] = (i + n/3)*114 + (j + n%3);
  }
  const int px_g = tid>>2;
  const int coff = (tid&3)*8;
  const unsigned short* ph_b = phi + (size_t)b*NPP*64;
  const unsigned short* pl_b = plo + (size_t)b*NPP*64;

  f32x4 acc[4][4] = {};
  __syncthreads();

  auto STAGE = [&](int kt, int buf){
    int n = kt>>1; int cb = ((kt&1)<<5) + coff;
    int pp = pp_tbl[px_g*9 + n];
    *(uint4*)&afh0[buf*2560 + px_g*40 + coff] = *(const uint4*)(ph_b + (size_t)pp*64 + cb);
    *(uint4*)&afl0[buf*2560 + px_g*40 + coff] = *(const uint4*)(pl_b + (size_t)pp*64 + cb);
  };

  const int klo = (lane>>4)<<3;
  STAGE(0, 0);
  for(int kt=0; kt<18; kt++){
    __syncthreads();
    if(kt+1 < 18) STAGE(kt+1, (kt+1)&1);
    const unsigned short* abh = afh0 + (kt&1)*2560;
    const unsigned short* abl = afl0 + (kt&1)*2560;
    short8 aH[4], aL[4];
    #pragma unroll
    for(int mf=0; mf<4; mf++){
      aH[mf] = *(const short8*)&abh[(mf*16 + (lane&15))*40 + klo];
      aL[mf] = *(const short8*)&abl[(mf*16 + (lane&15))*40 + klo];
    }
    #pragma unroll
    for(int nf=0; nf<4; nf++){
      int oc = wave*64 + nf*16 + (lane&15);
      short8 bH = *(const short8*)&w2fh[(size_t)kt*8192 + oc*32 + klo];
      short8 bL = *(const short8*)&w2fl[(size_t)kt*8192 + oc*32 + klo];
      #pragma unroll
      for(int mf=0; mf<4; mf++){
        acc[mf][nf] = __builtin_amdgcn_mfma_f32_16x16x32_bf16(aH[mf], bH, acc[mf][nf], 0,0,0);
        acc[mf][nf] = __builtin_amdgcn_mfma_f32_16x16x32_bf16(aH[mf], bL, acc[mf][nf], 0,0,0);
        acc[mf][nf] = __builtin_amdgcn_mfma_f32_16x16x32_bf16(aL[mf], bH, acc[mf][nf], 0,0,0);
      }
    }
  }
  // epilogue: two 32-px halves through tb (bias+relu), NHWC float4 stores + BN2 partials
  const int row0 = (lane>>4)<<2, col = lane&15;
  float s1q[4] = {0.f,0.f,0.f,0.f}, s2q[4] = {0.f,0.f,0.f,0.f};
  for(int half=0; half<2; half++){
    __syncthreads();
    #pragma unroll
    for(int m2=0; m2<2; m2++){
      int mf = half*2 + m2;
      #pragma unroll
      for(int nf=0; nf<4; nf++){
        int oc = wave*64 + nf*16 + col;
        #pragma unroll
        for(int r=0;r<4;r++) tb[(m2*16 + row0 + r)*257 + oc] = acc[mf][nf][r];
      }
    }
    __syncthreads();
    #pragma unroll
    for(int it=0; it<8; it++){
      int id = it*256 + tid;
      int pxl = id>>6, oc4 = id&63;            // oc4 == tid&63 (constant per thread)
      int px = half*32 + pxl;
      int ij = ij0+px; int i = ij/112, j = ij - i*112;
      int pp = (i+1)*114 + (j+1);
      float4 v;
      v.x = fmaxf(tb[pxl*257 + oc4*4+0] + b2[oc4*4+0], 0.f);
      v.y = fmaxf(tb[pxl*257 + oc4*4+1] + b2[oc4*4+1], 0.f);
      v.z = fmaxf(tb[pxl*257 + oc4*4+2] + b2[oc4*4+2], 0.f);
      v.w = fmaxf(tb[pxl*257 + oc4*4+3] + b2[oc4*4+3], 0.f);
      *(float4*)&hpad[((size_t)b*NPP + pp)*256 + oc4*4] = v;   // raw (pre-BN2)
      s1q[0] += v.x; s2q[0] += v.x*v.x;
      s1q[1] += v.y; s2q[1] += v.y*v.y;
      s1q[2] += v.z; s2q[2] += v.z*v.z;
      s1q[3] += v.w; s2q[3] += v.w*v.w;
    }
  }
  // block-level BN2 partial reduce through tb, one atomic pair per oc
  __syncthreads();
  #pragma unroll
  for(int q=0;q<4;q++){ tb[tid*4+q] = s1q[q]; tb[1024 + tid*4+q] = s2q[q]; }
  __syncthreads();
  {
    int oc = tid;                               // 256 ocs
    float s1 = ((tb[oc] + tb[256+oc]) + tb[512+oc]) + tb[768+oc];
    float s2 = ((tb[1024+oc] + tb[1280+oc]) + tb[1536+oc]) + tb[1792+oc];
    atomicAdd(&sum2[oc], s1); atomicAdd(&sum2[256+oc], s2);
  }
}

// ---- BN2 stats (per-block, redundant) + affine, 4-ch vectorized; bf16 hi/lo; band fp32 ----
__global__ __launch_bounds__(256) void k_affine2(float* __restrict__ hpad,
                          const float* __restrict__ sum2, const float* __restrict__ g2,
                          const float* __restrict__ be2,
                          unsigned short* __restrict__ hpadh, unsigned short* __restrict__ hpadl){
  __shared__ float sc_l[256], sh_l[256];
  int tid = threadIdx.x;
  {                                     // bit-identical to old k_fin2
    float n = 2.f*(float)NP2;
    float mean = sum2[tid]/n;
    float var  = sum2[256+tid]/n - mean*mean;
    float sc = g2[tid]/sqrtf(var + 1e-5f);
    sc_l[tid] = sc;
    sh_l[tid] = be2[tid] - mean*sc;
  }
  __syncthreads();
  int idx = blockIdx.x*256+tid;            // 1663488 = 6498*256
  int c4 = (idx & 63) << 2;                // 0,4,..252
  int pi = idx >> 6;                       // 0..25991
  int pp = pi % NPP;
  int row = pp/114, col = pp - row*114;
  bool in = (row>=1 && row<=112 && col>=1 && col<=112);
  float4 h = *(const float4*)&hpad[(size_t)pi*256 + c4];
  float4 v;
  v.x = in ? (sc_l[c4+0]*h.x + sh_l[c4+0]) : 0.f;
  v.y = in ? (sc_l[c4+1]*h.y + sh_l[c4+1]) : 0.f;
  v.z = in ? (sc_l[c4+2]*h.z + sh_l[c4+2]) : 0.f;
  v.w = in ? (sc_l[c4+3]*h.w + sh_l[c4+3]) : 0.f;
  // fp32 hpad is only consumed by k_offfix on the border band
  bool band = (row<6) || (row>107) || (col<6) || (col>107);
  if(band) *(float4*)&hpad[(size_t)pi*256 + c4] = v;
  unsigned short hx = f2bu(v.x), hy = f2bu(v.y), hz = f2bu(v.z), hw = f2bu(v.w);
  uint2 oh, ol;
  oh.x = (unsigned)hx | ((unsigned)hy<<16);
  oh.y = (unsigned)hz | ((unsigned)hw<<16);
  ol.x = (unsigned)f2bu(v.x - blo(hx)) | ((unsigned)f2bu(v.y - blo(hy))<<16);
  ol.y = (unsigned)f2bu(v.z - blo(hz)) | ((unsigned)f2bu(v.w - blo(hw))<<16);
  *(uint2*)&hpadh[(size_t)pi*256 + c4] = oh;
  *(uint2*)&hpadl[(size_t)pi*256 + c4] = ol;
}

// ---- offset conv, tap-split-K MFMA: 3 splits x 3 taps, grid 1176 = 8 xcd * 147 ----
__global__ __launch_bounds__(256) void k_convoff_mfma(
    const unsigned short* __restrict__ hpadh, const unsigned short* __restrict__ hpadl,
    const unsigned short* __restrict__ woffh, const unsigned short* __restrict__ woffl,
    float* __restrict__ p0, float* __restrict__ p1, float* __restrict__ p2){
  __shared__ int pp_tbl[192];                              // 64 px x 3 taps
  __shared__ __align__(16) unsigned short afh[2][64*72];   // 18432 B
  __shared__ __align__(16) unsigned short afl[2][64*72];   // 18432 B
  const int tid = threadIdx.x;
  const int wave = tid>>6, lane = tid&63;
  const int g = blockIdx.x;
  const int xcd = g & 7;
  const int rr  = g >> 3;               // 0..146
  const int split = rr % 3;             // k-split: taps split*3 .. +2
  const int sstrip = rr / 3;            // 0..48
  const int strip = xcd*49 + sstrip;    // 0..391
  const int pix0 = strip*64;
  const int b = pix0/NP2, ij0 = pix0 - b*NP2;
  const int n0 = split*3;

  for(int t=tid; t<192; t+=256){
    int p = t/3, nl = t - 3*(t/3);
    int ij = ij0+p; int i = ij/112, j = ij - i*112;
    int n = n0 + nl;
    pp_tbl[p*3+nl] = (i + n/3)*114 + (j + n%3);
  }
  const int px_g = tid>>2;              // 64 px, 4 thr/px
  const int coff = (tid&3)*16;          // 16-short (32B) slice of the 64-k phase
  const unsigned short* ph_b = hpadh + (size_t)b*NPP*256;
  const unsigned short* pl_b = hpadl + (size_t)b*NPP*256;
  const int r15 = lane&15, klo = (lane>>4)<<3;

  f32x4 acc[2] = {};
  __syncthreads();                      // pp_tbl ready

  auto STAGE = [&](int ph, int buf){    // ph = nl*4 + q : stages k = q*64..+63 of tap n0+nl
    int nl = ph>>2, q = ph&3;
    int pp = pp_tbl[px_g*3 + nl];
    int cb = q*64 + coff;
    uint4 h0 = *(const uint4*)(ph_b + (size_t)pp*256 + cb);
    uint4 h1 = *(const uint4*)(ph_b + (size_t)pp*256 + cb + 8);
    uint4 l0 = *(const uint4*)(pl_b + (size_t)pp*256 + cb);
    uint4 l1 = *(const uint4*)(pl_b + (size_t)pp*256 + cb + 8);
    *(uint4*)&afh[buf][px_g*72 + coff    ] = h0;
    *(uint4*)&afh[buf][px_g*72 + coff + 8] = h1;
    *(uint4*)&afl[buf][px_g*72 + coff    ] = l0;
    *(uint4*)&afl[buf][px_g*72 + coff + 8] = l1;
  };

  STAGE(0, 0);
  for(int ph=0; ph<12; ph++){
    __syncthreads();
    if(ph+1 < 12) STAGE(ph+1, (ph+1)&1);
    const unsigned short* ah = &afh[ph&1][(wave*16 + r15)*72];
    const unsigned short* al = &afl[ph&1][(wave*16 + r15)*72];
    const int n = n0 + (ph>>2), q = ph&3;
    #pragma unroll
    for(int half=0; half<2; half++){
      int kt = n*8 + q*2 + half;        // global k-tile index (B layout unchanged)
      short8 aH = *(const short8*)&ah[half*32 + klo];
      short8 aL = *(const short8*)&al[half*32 + klo];
      #pragma unroll
      for(int nf=0; nf<2; nf++){
        int oc = nf*16 + r15;
        short8 bH = *(const short8*)&woffh[(size_t)kt*1024 + oc*32 + klo];
        short8 bL = *(const short8*)&woffl[(size_t)kt*1024 + oc*32 + klo];
        acc[nf] = __builtin_amdgcn_mfma_f32_16x16x32_bf16(aH, bH, acc[nf], 0,0,0);
        acc[nf] = __builtin_amdgcn_mfma_f32_16x16x32_bf16(aH, bL, acc[nf], 0,0,0);
        acc[nf] = __builtin_amdgcn_mfma_f32_16x16x32_bf16(aL, bH, acc[nf], 0,0,0);
      }
    }
  }
  float* dst = (split==0) ? p0 : (split==1) ? p1 : p2;
  const int row0 = (lane>>4)<<2;
  #pragma unroll
  for(int nf=0; nf<2; nf++){
    int oc = nf*16 + r15;
    if(oc < 18)
      *(f32x4*)(dst + (size_t)(b*18+oc)*NP2 + ij0 + wave*16 + row0) = acc[nf];
  }
}

// ---- exact-fp32 recompute of offsets on the 3-wide border band (grid 327) ----
// Interior offb is left as the split-0 partial; k_deform combines partials inline.
__global__ __launch_bounds__(256) void k_offfix(const float* __restrict__ hpad,
        const float* __restrict__ woff2, const float* __restrict__ boff,
        float* __restrict__ offb){
  int idx = blockIdx.x*256 + threadIdx.x;   // 327*256 = 83712 = 2*1308*32
  if(idx >= 83712) return;
  int oc = idx & 31;
  int pid = idx >> 5;                       // 0..2615
  int b = pid / 1308; int t = pid - b*1308;
  int i, j;
  if(t < 672){                              // full rows 0,1,2,109,110,111
    int r = t/112; i = (r<3) ? r : 106+r; j = t - (t/112)*112;
  } else {                                  // cols 0,1,2,109,110,111 of rows 3..108
    int u = t - 672; i = 3 + u/6; int c6 = u - 6*(u/6);
    j = (c6<3) ? c6 : 106+c6;
  }
  const float* hb = hpad + (size_t)b*NPP*256;
  float a0=0.f, a1=0.f, a2=0.f, a3=0.f;     // 4 independent chains
  for(int n=0;n<9;n++){
    const float* ap = hb + (size_t)((i + n/3)*114 + (j + n%3))*256;
    const float* wp = woff2 + (size_t)n*256*32 + oc;
    #pragma unroll 4
    for(int c=0;c<256;c+=4){
      float4 a = *(const float4*)(ap + c);
      a0 = fmaf(a.x, wp[(c+0)*32], a0);
      a1 = fmaf(a.y, wp[(c+1)*32], a1);
      a2 = fmaf(a.z, wp[(c+2)*32], a2);
      a3 = fmaf(a.w, wp[(c+3)*32], a3);
    }
  }
  if(oc < 18)
    offb[(size_t)(b*18+oc)*NP2 + i*112 + j] = ((a0+a1)+(a2+a3)) + boff[oc];
}

// ---- deformable conv: MFMA bf16, M-tile 64, 36 merged phases (k=64 each), grid 392 ----
// Prologue combines the 3 convoff k-split partials inline for interior pixels;
// band pixels read the exact-fp32 offb written by k_offfix.
__global__ __launch_bounds__(256) void k_deform(
    const unsigned short* __restrict__ hpadh,       // NHWC bf16, affine'd, zero border
    const float* __restrict__ offb,                 // split-0 partial (interior) / exact (band)
    const float* __restrict__ p1, const float* __restrict__ p2,
    const float* __restrict__ boff,
    const unsigned short* __restrict__ w4f,         // frag-ready bf16 [72][256][32]
    float* __restrict__ out){
  __shared__ int   gidx[64][9][4];
  __shared__ float gwt [64][9][4];
  __shared__ __align__(16) unsigned short afrag[2][64*72];  // px stride 72 shorts (bank-safe)
  const int tid = threadIdx.x;
  const int wave = tid>>6, lane = tid&63;
  const int sidx = (blockIdx.x & 7)*49 + (blockIdx.x >> 3);
  const int pix0 = sidx*64;
  const int b = pix0/NP2, ij0 = pix0 - b*NP2;

  for(int t=tid; t<576; t+=256){
    int p = t/9, n = t - 9*(t/9);
    int ij = ij0+p; int i = ij/112, j = ij - i*112;
    size_t bx = (size_t)(b*18 + 2*n  )*NP2 + ij;
    size_t by = (size_t)(b*18 + 2*n+1)*NP2 + ij;
    bool band = (i<3) || (i>108) || (j<3) || (j>108);
    float ox, oy;
    if(band){                           // exact values from k_offfix
      ox = offb[bx]; oy = offb[by];
    } else {                            // inline 3-split combine (same order as old reduce)
      ox = ((offb[bx] + p1[bx]) + p2[bx]) + boff[2*n];
      oy = ((offb[by] + p1[by]) + p2[by]) + boff[2*n+1];
    }
    float px = (float)(i + n/3) + ox;
    float py = (float)(j + n%3) + oy;
    float fpx = floorf(px), fpy = floorf(py);
    float qltxf = fminf(fmaxf(fpx,     0.f),113.f);
    float qltyf = fminf(fmaxf(fpy,     0.f),113.f);
    float qrbxf = fminf(fmaxf(fpx+1.f, 0.f),113.f);
    float qrbyf = fminf(fmaxf(fpy+1.f, 0.f),113.f);
    int qltx=(int)qltxf, qlty=(int)qltyf, qrbx=(int)qrbxf, qrby=(int)qrbyf;
    bool mx = (px<1.f)||(px>112.f);
    bool my = (py<1.f)||(py>112.f);
    float pxc = fminf(fmaxf(mx?fpx:px, 0.f),113.f);
    float pyc = fminf(fmaxf(my?fpy:py, 0.f),113.f);
    float glt = (1.f+(qltxf-pxc))*(1.f+(qltyf-pyc));
    float grb = (1.f-(qrbxf-pxc))*(1.f-(qrbyf-pyc));
    float glb = (1.f+(qltxf-pxc))*(1.f-(qrbyf-pyc));
    float grt = (1.f-(qrbxf-pxc))*(1.f+(qltyf-pyc));
    gidx[p][n][0]=qltx*114+qlty; gwt[p][n][0]=glt;
    gidx[p][n][1]=qrbx*114+qrby; gwt[p][n][1]=grb;
    gidx[p][n][2]=qltx*114+qrby; gwt[p][n][2]=glb;  // (lt_x, rb_y)
    gidx[p][n][3]=qrbx*114+qlty; gwt[p][n][3]=grt;  // (rb_x, lt_y)
  }

  const int px_g   = tid>>2;            // 0..63
  const int coff_g = (tid&3)*8;         // 8-channel slice within each 32-ch k-chunk
  const unsigned short* hb = hpadh + (size_t)b*NPP*256;

  f32x4 acc[4][4] = {};
  __syncthreads();

  // phase ph covers tap n = ph>>2, channels (ph&3)*64 .. +63
  auto GATHER = [&](int ph, int buf){
    int n = ph>>2; int qb = (ph&3)<<6;
    const int*   gi = gidx[px_g][n];
    const float* gw = gwt[px_g][n];
    int i0 = gi[0], i1 = gi[1], i2 = gi[2], i3 = gi[3];
    float w0 = gw[0], w1 = gw[1], w2 = gw[2], w3 = gw[3];
    #pragma unroll
    for(int h=0; h<2; h++){
      int cb = qb + h*32 + coff_g;
      f32x4 va = {0.f,0.f,0.f,0.f}, vb = {0.f,0.f,0.f,0.f};
      const uint4 u0 = *(const uint4*)(hb + (size_t)i0*256 + cb);
      const uint4 u1 = *(const uint4*)(hb + (size_t)i1*256 + cb);
      const uint4 u2 = *(const uint4*)(hb + (size_t)i2*256 + cb);
      const uint4 u3 = *(const uint4*)(hb + (size_t)i3*256 + cb);
      // per-channel corner order 0,1,2,3 — identical to the 32-k version
      va.x = fmaf(w0, blo(u0.x), va.x); va.y = fmaf(w0, bhi(u0.x), va.y);
      va.z = fmaf(w0, blo(u0.y), va.z); va.w = fmaf(w0, bhi(u0.y), va.w);
      vb.x = fmaf(w0, blo(u0.z), vb.x); vb.y = fmaf(w0, bhi(u0.z), vb.y);
      vb.z = fmaf(w0, blo(u0.w), vb.z); vb.w = fmaf(w0, bhi(u0.w), vb.w);
      va.x = fmaf(w1, blo(u1.x), va.x); va.y = fmaf(w1, bhi(u1.x), va.y);
      va.z = fmaf(w1, blo(u1.y), va.z); va.w = fmaf(w1, bhi(u1.y), va.w);
      vb.x = fmaf(w1, blo(u1.z), vb.x); vb.y = fmaf(w1, bhi(u1.z), vb.y);
      vb.z = fmaf(w1, blo(u1.w), vb.z); vb.w = fmaf(w1, bhi(u1.w), vb.w);
      va.x = fmaf(w2, blo(u2.x), va.x); va.y = fmaf(w2, bhi(u2.x), va.y);
      va.z = fmaf(w2, blo(u2.y), va.z); va.w = fmaf(w2, bhi(u2.y), va.w);
      vb.x = fmaf(w2, blo(u2.z), vb.x); vb.y = fmaf(w2, bhi(u2.z), vb.y);
      vb.z = fmaf(w2, blo(u2.w), vb.z); vb.w = fmaf(w2, bhi(u2.w), vb.w);
      va.x = fmaf(w3, blo(u3.x), va.x); va.y = fmaf(w3, bhi(u3.x), va.y);
      va.z = fmaf(w3, blo(u3.y), va.z); va.w = fmaf(w3, bhi(u3.y), va.w);
      vb.x = fmaf(w3, blo(u3.z), vb.x); vb.y = fmaf(w3, bhi(u3.z), vb.y);
      vb.z = fmaf(w3, blo(u3.w), vb.z); vb.w = fmaf(w3, bhi(u3.w), vb.w);
      uint4 o;
      o.x = (unsigned)f2bu(va.x) | ((unsigned)f2bu(va.y)<<16);
      o.y = (unsigned)f2bu(va.z) | ((unsigned)f2bu(va.w)<<16);
      o.z = (unsigned)f2bu(vb.x) | ((unsigned)f2bu(vb.y)<<16);
      o.w = (unsigned)f2bu(vb.z) | ((unsigned)f2bu(vb.w)<<16);
      *(uint4*)&afrag[buf][px_g*72 + h*32 + coff_g] = o;
    }
  };

  const int klo = (lane>>4)<<3;         // k-slice within a 32-k chunk
  GATHER(0, 0);
  for(int ph=0; ph<36; ph++){
    __syncthreads();
    if(ph+1 < 36) GATHER(ph+1, (ph+1)&1);
    const unsigned short* ab = afrag[ph&1];
    #pragma unroll
    for(int h=0; h<2; h++){
      int kt = (ph>>2)*8 + (ph&3)*2 + h;
      short8 aF[4];
      #pragma unroll
      for(int mf=0; mf<4; mf++)
        aF[mf] = *(const short8*)&ab[(mf*16 + (lane&15))*72 + h*32 + klo];
      const unsigned short* wb = w4f + (size_t)kt*8192 + klo;
      #pragma unroll
      for(int nf=0; nf<4; nf++){
        int oc = wave*64 + nf*16 + (lane&15);
        short8 bF = *(const short8*)&wb[oc*32];
        #pragma unroll
        for(int mf=0; mf<4; mf++)
          acc[mf][nf] = __builtin_amdgcn_mfma_f32_16x16x32_bf16(aF[mf], bF, acc[mf][nf], 0,0,0);
      }
    }
  }
  int row0 = ((lane>>4)<<2);
  int col  = lane&15;
  #pragma unroll
  for(int mf=0; mf<4; mf++)
    #pragma unroll
    for(int nf=0; nf<4; nf++){
      int oc = wave*64 + nf*16 + col;
      size_t ob = (size_t)(b*256+oc)*NP2 + ij0 + mf*16 + row0;
      *(f32x4*)(out + ob) = acc[mf][nf];
    }
}

extern "C" void kernel_launch(void* const* d_in, const int* in_sizes, int n_in,
                              void* d_out, int out_size, void* d_ws, size_t ws_size,
                              hipStream_t stream){
  (void)in_sizes; (void)n_in;
  const float* x    = (const float*)d_in[0];
  const float* w1   = (const float*)d_in[1];
  const float* b1   = (const float*)d_in[2];
  const float* g1   = (const float*)d_in[3];
  const float* be1  = (const float*)d_in[4];
  const float* w2   = (const float*)d_in[5];
  const float* b2   = (const float*)d_in[6];
  const float* g2   = (const float*)d_in[7];
  const float* be2  = (const float*)d_in[8];
  const float* woff = (const float*)d_in[9];
  const float* boff = (const float*)d_in[10];
  const float* w4   = (const float*)d_in[11];
  float* out = (float*)d_out;
  float* ws = (float*)d_ws;

  if(ws_size < WS_NEED_BYTES){
    hipMemsetAsync(d_out, 0, (size_t)out_size*sizeof(float), stream);
    return;
  }

  float* sum1   = ws + S_SUM1;
  float* sum2   = ws + S_SUM2;
  float* woff2  = ws + S_WOFF2;
  unsigned short* w4f   = (unsigned short*)(ws + S_W4F);
  unsigned short* w2fh  = (unsigned short*)(ws + S_W2FH);
  unsigned short* w2fl  = (unsigned short*)(ws + S_W2FL);
  unsigned short* woffh = (unsigned short*)(ws + S_WOFFH);
  unsigned short* woffl = (unsigned short*)(ws + S_WOFFL);
  float* offb   = ws + S_OFFB;
  float* pooled = ws + S_PPAD;          // pooled NHWC (dead before convoff writes pb1 here)
  float* pb1    = ws + S_PPAD;          // convoff split-1 partial
  float* pb2    = ws + S_PB2;           // convoff split-2 partial
  unsigned short* phi = (unsigned short*)(ws + S_PHI);
  unsigned short* plo = (unsigned short*)(ws + S_PLO);
  float* hpad   = ws + S_HPAD;
  unsigned short* hpadh = (unsigned short*)(ws + S_HPADH);
  unsigned short* hpadl = (unsigned short*)(ws + S_HPADL);

  hipMemsetAsync(sum1, 0, 640*sizeof(float), stream);   // sum1(128) + sum2(512)
  k_conv1pool    <<<392,   256, 0, stream>>>(x, w1, b1, pooled, sum1,
                                             w4, woff, w2, w4f, woff2, woffh, woffl,
                                             w2fh, w2fl);
  k_affine1t     <<<3249,  256, 0, stream>>>(pooled, sum1, g1, be1, phi, plo);
  k_conv2        <<<392,   256, 0, stream>>>(phi, plo, w2fh, w2fl, b2, hpad, sum2);
  k_affine2      <<<6498,  256, 0, stream>>>(hpad, sum2, g2, be2, hpadh, hpadl);
  k_convoff_mfma <<<1176,  256, 0, stream>>>(hpadh, hpadl, woffh, woffl, offb, pb1, pb2);
  k_offfix       <<<327,   256, 0, stream>>>(hpad, woff2, boff, offb);
  k_deform       <<<392,   256, 0, stream>>>(hpadh, offb, pb1, pb2, boff, w4f, out);
}

// Round 17
// 342.116 us; speedup vs baseline: 1.0588x; 1.0109x over previous
//
#include <hip/hip_runtime.h>
#include <hip/hip_bf16.h>

#define NP1 50176      // 224*224
#define NP2 12544      // 112*112
#define NPP 12996      // 114*114 zero-padded map

typedef __attribute__((ext_vector_type(8))) short short8;   // 8 bf16 = 4 VGPRs
typedef __attribute__((ext_vector_type(4))) float f32x4;

__device__ __forceinline__ unsigned short f2bu(float f){
  __hip_bfloat16 h = __float2bfloat16(f);
  return *reinterpret_cast<unsigned short*>(&h);
}
__device__ __forceinline__ float blo(unsigned u){ union{unsigned q; float f;} x; x.q = u<<16; return x.f; }
__device__ __forceinline__ float bhi(unsigned u){ union{unsigned q; float f;} x; x.q = u & 0xffff0000u; return x.f; }

// ---- workspace layout (float slots) ----
#define S_SUM1   0          // 128
#define S_SUM2   128        // 512
#define S_WOFF2  1280       // 73728 fp32 (k = n*256+c, oc padded 32)
#define S_W4F    75008      // 294912 (589824 bf16 frag-ready)
#define S_W2FH   369920     // 73728 (147456 bf16: w2 hi, frag-ready [kt][oc][kk], k=n*64+c)
#define S_W2FL   443648     // 73728 (147456 bf16: w2 lo)
#define S_OFFB   517376     // 451584 fp32 (NCHW; interior = convoff split-0 PARTIAL, band = exact)
#define S_PPAD   968960     // 1663488 fp32 (pooled NHWC [2][112][112][64]; DEAD after k_conv2 -> convoff split-1 partial)
#define S_HPAD   4295936    // 6653952 fp32 (NHWC padded; post-affine values only on border band)
#define S_HPADL  10949888   // 3326976 (6653952 bf16 NHWC lo)
#define S_WOFFH  14276864   // 36864 (73728 bf16 frag-ready hi)
#define S_WOFFL  14313728   // 36864 (73728 bf16 frag-ready lo)
#define S_PB2    14350592   // 451584 fp32 (convoff split-2 partial)
#define S_HPADH  15014144   // 3326976 (6653952 bf16 NHWC hi)
#define WS_NEED_FLOATS 18341120ull
#define WS_NEED_BYTES  (WS_NEED_FLOATS*4ull)   // 73.4 MB

// ---- conv1+bias+ReLU + 2x2 avgpool (16 oc/block), NHWC pooled output,
//      fused weight-prep prologue. grid 392 = 2b * 4ocg * 49tiles. ----
__global__ __launch_bounds__(256) void k_conv1pool(
    const float* __restrict__ x, const float* __restrict__ w1, const float* __restrict__ b1,
    float* __restrict__ pooled, float* __restrict__ sum1,
    const float* __restrict__ w4, const float* __restrict__ woff, const float* __restrict__ w2,
    unsigned short* __restrict__ w4f, float* __restrict__ woff2,
    unsigned short* __restrict__ woffh, unsigned short* __restrict__ woffl,
    unsigned short* __restrict__ w2fh, unsigned short* __restrict__ w2fl){
  // ---- prologue: grid-stride over 884736 weight-prep jobs ----
  for(int t0 = blockIdx.x*256+threadIdx.x; t0 < 884736; t0 += 392*256){
    if(t0 < 589824){
      int kt = t0/8192; int r = t0 - kt*8192;
      int oc = r>>5, kk = r&31;
      int k = kt*32 + kk; int n = k>>8, c = k&255;
      w4f[t0] = f2bu(w4[oc*2304 + c*9 + n]);
    } else if(t0 < 663552){
      int i2 = t0 - 589824;                    // 73728
      int k = i2>>5, oc = i2&31;
      int n = k>>8, c = k&255;
      woff2[i2] = (oc<18) ? woff[oc*2304 + c*9 + n] : 0.f;
    } else if(t0 < 737280){
      int i3 = t0 - 663552;                    // 73728
      int kt = i3>>10; int r = i3 & 1023;
      int oc = r>>5, kk = r&31;
      int k = kt*32 + kk; int n = k>>8, c = k&255;
      float wv = (oc<18) ? woff[oc*2304 + c*9 + n] : 0.f;
      unsigned short hi = f2bu(wv);
      woffh[i3] = hi;
      woffl[i3] = f2bu(wv - blo(hi));
    } else {
      int i4 = t0 - 737280;                    // 147456
      int kt = i4/8192; int r = i4 - kt*8192;
      int oc = r>>5, kk = r&31;
      int k = kt*32 + kk; int n = k>>6, c = k&63;
      float wv = w2[oc*576 + c*9 + n];
      unsigned short hi = f2bu(wv);
      w2fh[i4] = hi;
      w2fl[i4] = f2bu(wv - blo(hi));
    }
  }
  // ---- main: conv1 + pool (values bit-identical; output layout NHWC) ----
  __shared__ float xs[3*34*34];         // 13872 B
  __shared__ float ws[16*28];           // 16 oc x 27 taps (stride 28)
  __shared__ float wbia[16];
  __shared__ float red[4][32];          // [wave][stat*16+o]
  int bid = blockIdx.x;                 // 392
  int tile = bid % 49; int ocg = (bid/49) & 3; int b = bid/(49*4);
  int oc0 = ocg*16;
  int tu = tile/7, tv = tile - 7*(tile/7);
  int tid = threadIdx.x;
  int in0 = tu*32 - 1, jn0 = tv*32 - 1;
  for(int t=tid; t<3468; t+=256){
    int c = t/1156; int r2 = t - c*1156; int rr = r2/34; int cc = r2 - rr*34;
    int ii = in0+rr, jj = jn0+cc;
    xs[t] = (ii>=0 && ii<224 && jj>=0 && jj<224) ? x[(size_t)(b*3+c)*NP1 + ii*224+jj] : 0.f;
  }
  for(int t=tid; t<432; t+=256){
    int o = t/27, q = t - o*27;
    ws[o*28+q] = w1[(oc0+o)*27+q];
  }
  if(tid<16) wbia[tid] = b1[oc0+tid];
  __syncthreads();
  int u = tid>>4, v = tid&15;           // pooled coords in tile
  float xw[3][4][4];
  #pragma unroll
  for(int c=0;c<3;c++)
    #pragma unroll
    for(int r=0;r<4;r++)
      #pragma unroll
      for(int cc=0;cc<4;cc++)
        xw[c][r][cc] = xs[c*1156 + (2*u+r)*34 + (2*v+cc)];
  float s1o[16], s2o[16], pv[16];
  int U = tu*16+u, V = tv*16+v;
  #pragma unroll 1
  for(int o=0;o<16;o++){
    float w27[27];
    #pragma unroll
    for(int q=0;q<27;q++) w27[q] = ws[o*28+q];
    float bia = wbia[o];
    float pl=0.f, s1=0.f, s2=0.f;
    #pragma unroll
    for(int dy=0;dy<2;dy++){
      #pragma unroll
      for(int dx=0;dx<2;dx++){
        float acc = bia;
        #pragma unroll
        for(int c=0;c<3;c++)
          #pragma unroll
          for(int kh=0;kh<3;kh++)
            #pragma unroll
            for(int kw=0;kw<3;kw++)
              acc += xw[c][dy+kh][dx+kw] * w27[c*9+kh*3+kw];
        acc = fmaxf(acc, 0.f);          // relu BEFORE BN
        pl += acc; s1 += acc; s2 += acc*acc;
      }
    }
    pv[o] = 0.25f*pl;
    s1o[o] = s1; s2o[o] = s2;
  }
  // NHWC pooled store: 16 consecutive channels of this px -> 4x float4
  {
    float* dst = pooled + ((size_t)b*NP2 + U*112 + V)*64 + oc0;
    #pragma unroll
    for(int q4=0;q4<4;q4++){
      float4 o4; o4.x=pv[q4*4+0]; o4.y=pv[q4*4+1]; o4.z=pv[q4*4+2]; o4.w=pv[q4*4+3];
      *(float4*)(dst + q4*4) = o4;
    }
  }
  const int lane = tid&63, wv = tid>>6;
  #pragma unroll 1
  for(int o=0;o<16;o++){
    float a = s1o[o], c2 = s2o[o];
    #pragma unroll
    for(int off=32; off; off>>=1){
      a  += __shfl_down(a,  off, 64);
      c2 += __shfl_down(c2, off, 64);
    }
    if(lane==0){ red[wv][o] = a; red[wv][16+o] = c2; }
  }
  __syncthreads();
  if(tid<32){
    int o = tid&15, st = tid>>4;
    float v4 = ((red[0][st*16+o] + red[1][st*16+o]) + red[2][st*16+o]) + red[3][st*16+o];
    atomicAdd(&sum1[st*64 + oc0 + o], v4);
  }
}

// ---- conv2: MFMA bf16x2, M-tile 64, N=256, K=576.
//      BN1 affine + bf16 hi/lo split fused into STAGE (reads pooled fp32 directly —
//      same 32B/thread as the old phi+plo reads; k_affine1t deleted).
//      BN2 partial stats fused in epilogue. ----
__global__ __launch_bounds__(256) void k_conv2(
    const float* __restrict__ pooled,
    const float* __restrict__ sum1, const float* __restrict__ g1,
    const float* __restrict__ be1,
    const unsigned short* __restrict__ w2fh, const unsigned short* __restrict__ w2fl,
    const float* __restrict__ b2, float* __restrict__ hpad, float* __restrict__ sum2){
  __shared__ float smemf[8800];   // pp_tbl[576 ints] | af(5120 floats) ∪ tb(8224 floats)
  __shared__ float sc_l[64], sh_l[64];
  int*  pp_tbl = (int*)smemf;
  unsigned short* afh0 = (unsigned short*)(smemf + 576);    // 2*64*40 shorts = 2560 floats
  unsigned short* afl0 = (unsigned short*)(smemf + 576 + 2560);
  float* tb = smemf + 576;
  const int tid = threadIdx.x;
  const int wave = tid>>6, lane = tid&63;
  const int sidx = (blockIdx.x & 7)*49 + (blockIdx.x >> 3);  // XCD swizzle, grid 392
  const int pix0 = sidx*64;
  const int b = pix0/NP2, ij0 = pix0 - b*NP2;

  if(tid < 64){                         // BN1 stats, bit-identical to old k_fin1/affine1t
    float n = 2.f*(float)NP1;
    float mean = sum1[tid]/n;
    float var  = sum1[64+tid]/n - mean*mean;
    float sc = g1[tid]/sqrtf(var + 1e-5f);
    sc_l[tid] = sc;
    sh_l[tid] = be1[tid] - mean*sc;
  }
  for(int t=tid; t<576; t+=256){
    int p = t/9, n = t - 9*(t/9);
    int ij = ij0+p; int i = ij/112, j = ij - i*112;
    int pr = i + n/3, pc = j + n%3;     // padded coords 0..113
    bool bord = (pr==0) || (pr==113) || (pc==0) || (pc==113);
    pp_tbl[p*9+n] = bord ? -1 : ((pr-1)*112 + (pc-1));   // pooled px index or border flag
  }
  const int px_g = tid>>2;
  const int coff = (tid&3)*8;
  const float* po_b = pooled + (size_t)b*NP2*64;

  f32x4 acc[4][4] = {};
  __syncthreads();

  auto STAGE = [&](int kt, int buf){
    int n = kt>>1; int cb = ((kt&1)<<5) + coff;
    int pp = pp_tbl[px_g*9 + n];
    uint4 oh = {0u,0u,0u,0u}, ol = {0u,0u,0u,0u};       // border -> zeros (as affine1t did)
    if(pp >= 0){
      const float* src = po_b + (size_t)pp*64 + cb;
      float4 a4 = *(const float4*)src;
      float4 b4 = *(const float4*)(src+4);
      float v0 = sc_l[cb+0]*a4.x + sh_l[cb+0];
      float v1 = sc_l[cb+1]*a4.y + sh_l[cb+1];
      float v2 = sc_l[cb+2]*a4.z + sh_l[cb+2];
      float v3 = sc_l[cb+3]*a4.w + sh_l[cb+3];
      float v4 = sc_l[cb+4]*b4.x + sh_l[cb+4];
      float v5 = sc_l[cb+5]*b4.y + sh_l[cb+5];
      float v6 = sc_l[cb+6]*b4.z + sh_l[cb+6];
      float v7 = sc_l[cb+7]*b4.w + sh_l[cb+7];
      unsigned short h0=f2bu(v0), h1=f2bu(v1), h2=f2bu(v2), h3=f2bu(v3);
      unsigned short h4=f2bu(v4), h5=f2bu(v5), h6=f2bu(v6), h7=f2bu(v7);
      oh.x = (unsigned)h0 | ((unsigned)h1<<16);
      oh.y = (unsigned)h2 | ((unsigned)h3<<16);
      oh.z = (unsigned)h4 | ((unsigned)h5<<16);
      oh.w = (unsigned)h6 | ((unsigned)h7<<16);
      ol.x = (unsigned)f2bu(v0 - blo(h0)) | ((unsigned)f2bu(v1 - blo(h1))<<16);
      ol.y = (unsigned)f2bu(v2 - blo(h2)) | ((unsigned)f2bu(v3 - blo(h3))<<16);
      ol.z = (unsigned)f2bu(v4 - blo(h4)) | ((unsigned)f2bu(v5 - blo(h5))<<16);
      ol.w = (unsigned)f2bu(v6 - blo(h6)) | ((unsigned)f2bu(v7 - blo(h7))<<16);
    }
    *(uint4*)&afh0[buf*2560 + px_g*40 + coff] = oh;
    *(uint4*)&afl0[buf*2560 + px_g*40 + coff] = ol;
  };

  const int klo = (lane>>4)<<3;
  STAGE(0, 0);
  for(int kt=0; kt<18; kt++){
    __syncthreads();
    if(kt+1 < 18) STAGE(kt+1, (kt+1)&1);
    const unsigned short* abh = afh0 + (kt&1)*2560;
    const unsigned short* abl = afl0 + (kt&1)*2560;
    short8 aH[4], aL[4];
    #pragma unroll
    for(int mf=0; mf<4; mf++){
      aH[mf] = *(const short8*)&abh[(mf*16 + (lane&15))*40 + klo];
      aL[mf] = *(const short8*)&abl[(mf*16 + (lane&15))*40 + klo];
    }
    #pragma unroll
    for(int nf=0; nf<4; nf++){
      int oc = wave*64 + nf*16 + (lane&15);
      short8 bH = *(const short8*)&w2fh[(size_t)kt*8192 + oc*32 + klo];
      short8 bL = *(const short8*)&w2fl[(size_t)kt*8192 + oc*32 + klo];
      #pragma unroll
      for(int mf=0; mf<4; mf++){
        acc[mf][nf] = __builtin_amdgcn_mfma_f32_16x16x32_bf16(aH[mf], bH, acc[mf][nf], 0,0,0);
        acc[mf][nf] = __builtin_amdgcn_mfma_f32_16x16x32_bf16(aH[mf], bL, acc[mf][nf], 0,0,0);
        acc[mf][nf] = __builtin_amdgcn_mfma_f32_16x16x32_bf16(aL[mf], bH, acc[mf][nf], 0,0,0);
      }
    }
  }
  // epilogue: two 32-px halves through tb (bias+relu), NHWC float4 stores + BN2 partials
  const int row0 = (lane>>4)<<2, col = lane&15;
  float s1q[4] = {0.f,0.f,0.f,0.f}, s2q[4] = {0.f,0.f,0.f,0.f};
  for(int half=0; half<2; half++){
    __syncthreads();
    #pragma unroll
    for(int m2=0; m2<2; m2++){
      int mf = half*2 + m2;
      #pragma unroll
      for(int nf=0; nf<4; nf++){
        int oc = wave*64 + nf*16 + col;
        #pragma unroll
        for(int r=0;r<4;r++) tb[(m2*16 + row0 + r)*257 + oc] = acc[mf][nf][r];
      }
    }
    __syncthreads();
    #pragma unroll
    for(int it=0; it<8; it++){
      int id = it*256 + tid;
      int pxl = id>>6, oc4 = id&63;            // oc4 == tid&63 (constant per thread)
      int px = half*32 + pxl;
      int ij = ij0+px; int i = ij/112, j = ij - i*112;
      int pp = (i+1)*114 + (j+1);
      float4 v;
      v.x = fmaxf(tb[pxl*257 + oc4*4+0] + b2[oc4*4+0], 0.f);
      v.y = fmaxf(tb[pxl*257 + oc4*4+1] + b2[oc4*4+1], 0.f);
      v.z = fmaxf(tb[pxl*257 + oc4*4+2] + b2[oc4*4+2], 0.f);
      v.w = fmaxf(tb[pxl*257 + oc4*4+3] + b2[oc4*4+3], 0.f);
      *(float4*)&hpad[((size_t)b*NPP + pp)*256 + oc4*4] = v;   // raw (pre-BN2)
      s1q[0] += v.x; s2q[0] += v.x*v.x;
      s1q[1] += v.y; s2q[1] += v.y*v.y;
      s1q[2] += v.z; s2q[2] += v.z*v.z;
      s1q[3] += v.w; s2q[3] += v.w*v.w;
    }
  }
  // block-level BN2 partial reduce through tb, one atomic pair per oc
  __syncthreads();
  #pragma unroll
  for(int q=0;q<4;q++){ tb[tid*4+q] = s1q[q]; tb[1024 + tid*4+q] = s2q[q]; }
  __syncthreads();
  {
    int oc = tid;                               // 256 ocs
    float s1 = ((tb[oc] + tb[256+oc]) + tb[512+oc]) + tb[768+oc];
    float s2 = ((tb[1024+oc] + tb[1280+oc]) + tb[1536+oc]) + tb[1792+oc];
    atomicAdd(&sum2[oc], s1); atomicAdd(&sum2[256+oc], s2);
  }
}

// ---- BN2 stats (per-block, redundant) + affine, 4-ch vectorized; bf16 hi/lo; band fp32 ----
__global__ __launch_bounds__(256) void k_affine2(float* __restrict__ hpad,
                          const float* __restrict__ sum2, const float* __restrict__ g2,
                          const float* __restrict__ be2,
                          unsigned short* __restrict__ hpadh, unsigned short* __restrict__ hpadl){
  __shared__ float sc_l[256], sh_l[256];
  int tid = threadIdx.x;
  {                                     // bit-identical to old k_fin2
    float n = 2.f*(float)NP2;
    float mean = sum2[tid]/n;
    float var  = sum2[256+tid]/n - mean*mean;
    float sc = g2[tid]/sqrtf(var + 1e-5f);
    sc_l[tid] = sc;
    sh_l[tid] = be2[tid] - mean*sc;
  }
  __syncthreads();
  int idx = blockIdx.x*256+tid;            // 1663488 = 6498*256
  int c4 = (idx & 63) << 2;                // 0,4,..252
  int pi = idx >> 6;                       // 0..25991
  int pp = pi % NPP;
  int row = pp/114, col = pp - row*114;
  bool in = (row>=1 && row<=112 && col>=1 && col<=112);
  float4 h = *(const float4*)&hpad[(size_t)pi*256 + c4];
  float4 v;
  v.x = in ? (sc_l[c4+0]*h.x + sh_l[c4+0]) : 0.f;
  v.y = in ? (sc_l[c4+1]*h.y + sh_l[c4+1]) : 0.f;
  v.z = in ? (sc_l[c4+2]*h.z + sh_l[c4+2]) : 0.f;
  v.w = in ? (sc_l[c4+3]*h.w + sh_l[c4+3]) : 0.f;
  // fp32 hpad is only consumed by k_offfix on the border band
  bool band = (row<6) || (row>107) || (col<6) || (col>107);
  if(band) *(float4*)&hpad[(size_t)pi*256 + c4] = v;
  unsigned short hx = f2bu(v.x), hy = f2bu(v.y), hz = f2bu(v.z), hw = f2bu(v.w);
  uint2 oh, ol;
  oh.x = (unsigned)hx | ((unsigned)hy<<16);
  oh.y = (unsigned)hz | ((unsigned)hw<<16);
  ol.x = (unsigned)f2bu(v.x - blo(hx)) | ((unsigned)f2bu(v.y - blo(hy))<<16);
  ol.y = (unsigned)f2bu(v.z - blo(hz)) | ((unsigned)f2bu(v.w - blo(hw))<<16);
  *(uint2*)&hpadh[(size_t)pi*256 + c4] = oh;
  *(uint2*)&hpadl[(size_t)pi*256 + c4] = ol;
}

// ---- offset conv, tap-split-K MFMA: 3 splits x 3 taps, grid 1176 = 8 xcd * 147 ----
__global__ __launch_bounds__(256) void k_convoff_mfma(
    const unsigned short* __restrict__ hpadh, const unsigned short* __restrict__ hpadl,
    const unsigned short* __restrict__ woffh, const unsigned short* __restrict__ woffl,
    float* __restrict__ p0, float* __restrict__ p1, float* __restrict__ p2){
  __shared__ int pp_tbl[192];                              // 64 px x 3 taps
  __shared__ __align__(16) unsigned short afh[2][64*72];   // 18432 B
  __shared__ __align__(16) unsigned short afl[2][64*72];   // 18432 B
  const int tid = threadIdx.x;
  const int wave = tid>>6, lane = tid&63;
  const int g = blockIdx.x;
  const int xcd = g & 7;
  const int rr  = g >> 3;               // 0..146
  const int split = rr % 3;             // k-split: taps split*3 .. +2
  const int sstrip = rr / 3;            // 0..48
  const int strip = xcd*49 + sstrip;    // 0..391
  const int pix0 = strip*64;
  const int b = pix0/NP2, ij0 = pix0 - b*NP2;
  const int n0 = split*3;

  for(int t=tid; t<192; t+=256){
    int p = t/3, nl = t - 3*(t/3);
    int ij = ij0+p; int i = ij/112, j = ij - i*112;
    int n = n0 + nl;
    pp_tbl[p*3+nl] = (i + n/3)*114 + (j + n%3);
  }
  const int px_g = tid>>2;              // 64 px, 4 thr/px
  const int coff = (tid&3)*16;          // 16-short (32B) slice of the 64-k phase
  const unsigned short* ph_b = hpadh + (size_t)b*NPP*256;
  const unsigned short* pl_b = hpadl + (size_t)b*NPP*256;
  const int r15 = lane&15, klo = (lane>>4)<<3;

  f32x4 acc[2] = {};
  __syncthreads();                      // pp_tbl ready

  auto STAGE = [&](int ph, int buf){    // ph = nl*4 + q : stages k = q*64..+63 of tap n0+nl
    int nl = ph>>2, q = ph&3;
    int pp = pp_tbl[px_g*3 + nl];
    int cb = q*64 + coff;
    uint4 h0 = *(const uint4*)(ph_b + (size_t)pp*256 + cb);
    uint4 h1 = *(const uint4*)(ph_b + (size_t)pp*256 + cb + 8);
    uint4 l0 = *(const uint4*)(pl_b + (size_t)pp*256 + cb);
    uint4 l1 = *(const uint4*)(pl_b + (size_t)pp*256 + cb + 8);
    *(uint4*)&afh[buf][px_g*72 + coff    ] = h0;
    *(uint4*)&afh[buf][px_g*72 + coff + 8] = h1;
    *(uint4*)&afl[buf][px_g*72 + coff    ] = l0;
    *(uint4*)&afl[buf][px_g*72 + coff + 8] = l1;
  };

  STAGE(0, 0);
  for(int ph=0; ph<12; ph++){
    __syncthreads();
    if(ph+1 < 12) STAGE(ph+1, (ph+1)&1);
    const unsigned short* ah = &afh[ph&1][(wave*16 + r15)*72];
    const unsigned short* al = &afl[ph&1][(wave*16 + r15)*72];
    const int n = n0 + (ph>>2), q = ph&3;
    #pragma unroll
    for(int half=0; half<2; half++){
      int kt = n*8 + q*2 + half;        // global k-tile index (B layout unchanged)
      short8 aH = *(const short8*)&ah[half*32 + klo];
      short8 aL = *(const short8*)&al[half*32 + klo];
      #pragma unroll
      for(int nf=0; nf<2; nf++){
        int oc = nf*16 + r15;
        short8 bH = *(const short8*)&woffh[(size_t)kt*1024 + oc*32 + klo];
        short8 bL = *(const short8*)&woffl[(size_t)kt*1024 + oc*32 + klo];
        acc[nf] = __builtin_amdgcn_mfma_f32_16x16x32_bf16(aH, bH, acc[nf], 0,0,0);
        acc[nf] = __builtin_amdgcn_mfma_f32_16x16x32_bf16(aH, bL, acc[nf], 0,0,0);
        acc[nf] = __builtin_amdgcn_mfma_f32_16x16x32_bf16(aL, bH, acc[nf], 0,0,0);
      }
    }
  }
  float* dst = (split==0) ? p0 : (split==1) ? p1 : p2;
  const int row0 = (lane>>4)<<2;
  #pragma unroll
  for(int nf=0; nf<2; nf++){
    int oc = nf*16 + r15;
    if(oc < 18)
      *(f32x4*)(dst + (size_t)(b*18+oc)*NP2 + ij0 + wave*16 + row0) = acc[nf];
  }
}

// ---- exact-fp32 recompute of offsets on the 3-wide border band (grid 327) ----
// Interior offb is left as the split-0 partial; k_deform combines partials inline.
__global__ __launch_bounds__(256) void k_offfix(const float* __restrict__ hpad,
        const float* __restrict__ woff2, const float* __restrict__ boff,
        float* __restrict__ offb){
  int idx = blockIdx.x*256 + threadIdx.x;   // 327*256 = 83712 = 2*1308*32
  if(idx >= 83712) return;
  int oc = idx & 31;
  int pid = idx >> 5;                       // 0..2615
  int b = pid / 1308; int t = pid - b*1308;
  int i, j;
  if(t < 672){                              // full rows 0,1,2,109,110,111
    int r = t/112; i = (r<3) ? r : 106+r; j = t - (t/112)*112;
  } else {                                  // cols 0,1,2,109,110,111 of rows 3..108
    int u = t - 672; i = 3 + u/6; int c6 = u - 6*(u/6);
    j = (c6<3) ? c6 : 106+c6;
  }
  const float* hb = hpad + (size_t)b*NPP*256;
  float a0=0.f, a1=0.f, a2=0.f, a3=0.f;     // 4 independent chains
  for(int n=0;n<9;n++){
    const float* ap = hb + (size_t)((i + n/3)*114 + (j + n%3))*256;
    const float* wp = woff2 + (size_t)n*256*32 + oc;
    #pragma unroll 4
    for(int c=0;c<256;c+=4){
      float4 a = *(const float4*)(ap + c);
      a0 = fmaf(a.x, wp[(c+0)*32], a0);
      a1 = fmaf(a.y, wp[(c+1)*32], a1);
      a2 = fmaf(a.z, wp[(c+2)*32], a2);
      a3 = fmaf(a.w, wp[(c+3)*32], a3);
    }
  }
  if(oc < 18)
    offb[(size_t)(b*18+oc)*NP2 + i*112 + j] = ((a0+a1)+(a2+a3)) + boff[oc];
}

// ---- deformable conv: MFMA bf16, M-tile 64, 36 merged phases (k=64 each), grid 392 ----
// Prologue combines the 3 convoff k-split partials inline for interior pixels;
// band pixels read the exact-fp32 offb written by k_offfix.
__global__ __launch_bounds__(256) void k_deform(
    const unsigned short* __restrict__ hpadh,       // NHWC bf16, affine'd, zero border
    const float* __restrict__ offb,                 // split-0 partial (interior) / exact (band)
    const float* __restrict__ p1, const float* __restrict__ p2,
    const float* __restrict__ boff,
    const unsigned short* __restrict__ w4f,         // frag-ready bf16 [72][256][32]
    float* __restrict__ out){
  __shared__ int   gidx[64][9][4];
  __shared__ float gwt [64][9][4];
  __shared__ __align__(16) unsigned short afrag[2][64*72];  // px stride 72 shorts (bank-safe)
  const int tid = threadIdx.x;
  const int wave = tid>>6, lane = tid&63;
  const int sidx = (blockIdx.x & 7)*49 + (blockIdx.x >> 3);
  const int pix0 = sidx*64;
  const int b = pix0/NP2, ij0 = pix0 - b*NP2;

  for(int t=tid; t<576; t+=256){
    int p = t/9, n = t - 9*(t/9);
    int ij = ij0+p; int i = ij/112, j = ij - i*112;
    size_t bx = (size_t)(b*18 + 2*n  )*NP2 + ij;
    size_t by = (size_t)(b*18 + 2*n+1)*NP2 + ij;
    bool band = (i<3) || (i>108) || (j<3) || (j>108);
    float ox, oy;
    if(band){                           // exact values from k_offfix
      ox = offb[bx]; oy = offb[by];
    } else {                            // inline 3-split combine (same order as old reduce)
      ox = ((offb[bx] + p1[bx]) + p2[bx]) + boff[2*n];
      oy = ((offb[by] + p1[by]) + p2[by]) + boff[2*n+1];
    }
    float px = (float)(i + n/3) + ox;
    float py = (float)(j + n%3) + oy;
    float fpx = floorf(px), fpy = floorf(py);
    float qltxf = fminf(fmaxf(fpx,     0.f),113.f);
    float qltyf = fminf(fmaxf(fpy,     0.f),113.f);
    float qrbxf = fminf(fmaxf(fpx+1.f, 0.f),113.f);
    float qrbyf = fminf(fmaxf(fpy+1.f, 0.f),113.f);
    int qltx=(int)qltxf, qlty=(int)qltyf, qrbx=(int)qrbxf, qrby=(int)qrbyf;
    bool mx = (px<1.f)||(px>112.f);
    bool my = (py<1.f)||(py>112.f);
    float pxc = fminf(fmaxf(mx?fpx:px, 0.f),113.f);
    float pyc = fminf(fmaxf(my?fpy:py, 0.f),113.f);
    float glt = (1.f+(qltxf-pxc))*(1.f+(qltyf-pyc));
    float grb = (1.f-(qrbxf-pxc))*(1.f-(qrbyf-pyc));
    float glb = (1.f+(qltxf-pxc))*(1.f-(qrbyf-pyc));
    float grt = (1.f-(qrbxf-pxc))*(1.f+(qltyf-pyc));
    gidx[p][n][0]=qltx*114+qlty; gwt[p][n][0]=glt;
    gidx[p][n][1]=qrbx*114+qrby; gwt[p][n][1]=grb;
    gidx[p][n][2]=qltx*114+qrby; gwt[p][n][2]=glb;  // (lt_x, rb_y)
    gidx[p][n][3]=qrbx*114+qlty; gwt[p][n][3]=grt;  // (rb_x, lt_y)
  }

  const int px_g   = tid>>2;            // 0..63
  const int coff_g = (tid&3)*8;         // 8-channel slice within each 32-ch k-chunk
  const unsigned short* hb = hpadh + (size_t)b*NPP*256;

  f32x4 acc[4][4] = {};
  __syncthreads();

  // phase ph covers tap n = ph>>2, channels (ph&3)*64 .. +63
  auto GATHER = [&](int ph, int buf){
    int n = ph>>2; int qb = (ph&3)<<6;
    const int*   gi = gidx[px_g][n];
    const float* gw = gwt[px_g][n];
    int i0 = gi[0], i1 = gi[1], i2 = gi[2], i3 = gi[3];
    float w0 = gw[0], w1 = gw[1], w2 = gw[2], w3 = gw[3];
    #pragma unroll
    for(int h=0; h<2; h++){
      int cb = qb + h*32 + coff_g;
      f32x4 va = {0.f,0.f,0.f,0.f}, vb = {0.f,0.f,0.f,0.f};
      const uint4 u0 = *(const uint4*)(hb + (size_t)i0*256 + cb);
      const uint4 u1 = *(const uint4*)(hb + (size_t)i1*256 + cb);
      const uint4 u2 = *(const uint4*)(hb + (size_t)i2*256 + cb);
      const uint4 u3 = *(const uint4*)(hb + (size_t)i3*256 + cb);
      // per-channel corner order 0,1,2,3 — identical to the 32-k version
      va.x = fmaf(w0, blo(u0.x), va.x); va.y = fmaf(w0, bhi(u0.x), va.y);
      va.z = fmaf(w0, blo(u0.y), va.z); va.w = fmaf(w0, bhi(u0.y), va.w);
      vb.x = fmaf(w0, blo(u0.z), vb.x); vb.y = fmaf(w0, bhi(u0.z), vb.y);
      vb.z = fmaf(w0, blo(u0.w), vb.z); vb.w = fmaf(w0, bhi(u0.w), vb.w);
      va.x = fmaf(w1, blo(u1.x), va.x); va.y = fmaf(w1, bhi(u1.x), va.y);
      va.z = fmaf(w1, blo(u1.y), va.z); va.w = fmaf(w1, bhi(u1.y), va.w);
      vb.x = fmaf(w1, blo(u1.z), vb.x); vb.y = fmaf(w1, bhi(u1.z), vb.y);
      vb.z = fmaf(w1, blo(u1.w), vb.z); vb.w = fmaf(w1, bhi(u1.w), vb.w);
      va.x = fmaf(w2, blo(u2.x), va.x); va.y = fmaf(w2, bhi(u2.x), va.y);
      va.z = fmaf(w2, blo(u2.y), va.z); va.w = fmaf(w2, bhi(u2.y), va.w);
      vb.x = fmaf(w2, blo(u2.z), vb.x); vb.y = fmaf(w2, bhi(u2.z), vb.y);
      vb.z = fmaf(w2, blo(u2.w), vb.z); vb.w = fmaf(w2, bhi(u2.w), vb.w);
      va.x = fmaf(w3, blo(u3.x), va.x); va.y = fmaf(w3, bhi(u3.x), va.y);
      va.z = fmaf(w3, blo(u3.y), va.z); va.w = fmaf(w3, bhi(u3.y), va.w);
      vb.x = fmaf(w3, blo(u3.z), vb.x); vb.y = fmaf(w3, bhi(u3.z), vb.y);
      vb.z = fmaf(w3, blo(u3.w), vb.z); vb.w = fmaf(w3, bhi(u3.w), vb.w);
      uint4 o;
      o.x = (unsigned)f2bu(va.x) | ((unsigned)f2bu(va.y)<<16);
      o.y = (unsigned)f2bu(va.z) | ((unsigned)f2bu(va.w)<<16);
      o.z = (unsigned)f2bu(vb.x) | ((unsigned)f2bu(vb.y)<<16);
      o.w = (unsigned)f2bu(vb.z) | ((unsigned)f2bu(vb.w)<<16);
      *(uint4*)&afrag[buf][px_g*72 + h*32 + coff_g] = o;
    }
  };

  const int klo = (lane>>4)<<3;         // k-slice within a 32-k chunk
  GATHER(0, 0);
  for(int ph=0; ph<36; ph++){
    __syncthreads();
    if(ph+1 < 36) GATHER(ph+1, (ph+1)&1);
    const unsigned short* ab = afrag[ph&1];
    #pragma unroll
    for(int h=0; h<2; h++){
      int kt = (ph>>2)*8 + (ph&3)*2 + h;
      short8 aF[4];
      #pragma unroll
      for(int mf=0; mf<4; mf++)
        aF[mf] = *(const short8*)&ab[(mf*16 + (lane&15))*72 + h*32 + klo];
      const unsigned short* wb = w4f + (size_t)kt*8192 + klo;
      #pragma unroll
      for(int nf=0; nf<4; nf++){
        int oc = wave*64 + nf*16 + (lane&15);
        short8 bF = *(const short8*)&wb[oc*32];
        #pragma unroll
        for(int mf=0; mf<4; mf++)
          acc[mf][nf] = __builtin_amdgcn_mfma_f32_16x16x32_bf16(aF[mf], bF, acc[mf][nf], 0,0,0);
      }
    }
  }
  int row0 = ((lane>>4)<<2);
  int col  = lane&15;
  #pragma unroll
  for(int mf=0; mf<4; mf++)
    #pragma unroll
    for(int nf=0; nf<4; nf++){
      int oc = wave*64 + nf*16 + col;
      size_t ob = (size_t)(b*256+oc)*NP2 + ij0 + mf*16 + row0;
      *(f32x4*)(out + ob) = acc[mf][nf];
    }
}

extern "C" void kernel_launch(void* const* d_in, const int* in_sizes, int n_in,
                              void* d_out, int out_size, void* d_ws, size_t ws_size,
                              hipStream_t stream){
  (void)in_sizes; (void)n_in;
  const float* x    = (const float*)d_in[0];
  const float* w1   = (const float*)d_in[1];
  const float* b1   = (const float*)d_in[2];
  const float* g1   = (const float*)d_in[3];
  const float* be1  = (const float*)d_in[4];
  const float* w2   = (const float*)d_in[5];
  const float* b2   = (const float*)d_in[6];
  const float* g2   = (const float*)d_in[7];
  const float* be2  = (const float*)d_in[8];
  const float* woff = (const float*)d_in[9];
  const float* boff = (const float*)d_in[10];
  const float* w4   = (const float*)d_in[11];
  float* out = (float*)d_out;
  float* ws = (float*)d_ws;

  if(ws_size < WS_NEED_BYTES){
    hipMemsetAsync(d_out, 0, (size_t)out_size*sizeof(float), stream);
    return;
  }

  float* sum1   = ws + S_SUM1;
  float* sum2   = ws + S_SUM2;
  float* woff2  = ws + S_WOFF2;
  unsigned short* w4f   = (unsigned short*)(ws + S_W4F);
  unsigned short* w2fh  = (unsigned short*)(ws + S_W2FH);
  unsigned short* w2fl  = (unsigned short*)(ws + S_W2FL);
  unsigned short* woffh = (unsigned short*)(ws + S_WOFFH);
  unsigned short* woffl = (unsigned short*)(ws + S_WOFFL);
  float* offb   = ws + S_OFFB;
  float* pooled = ws + S_PPAD;          // pooled NHWC (dead before convoff writes pb1 here)
  float* pb1    = ws + S_PPAD;          // convoff split-1 partial
  float* pb2    = ws + S_PB2;           // convoff split-2 partial
  float* hpad   = ws + S_HPAD;
  unsigned short* hpadh = (unsigned short*)(ws + S_HPADH);
  unsigned short* hpadl = (unsigned short*)(ws + S_HPADL);

  hipMemsetAsync(sum1, 0, 640*sizeof(float), stream);   // sum1(128) + sum2(512)
  k_conv1pool    <<<392,   256, 0, stream>>>(x, w1, b1, pooled, sum1,
                                             w4, woff, w2, w4f, woff2, woffh, woffl,
                                             w2fh, w2fl);
  k_conv2        <<<392,   256, 0, stream>>>(pooled, sum1, g1, be1,
                                             w2fh, w2fl, b2, hpad, sum2);
  k_affine2      <<<6498,  256, 0, stream>>>(hpad, sum2, g2, be2, hpadh, hpadl);
  k_convoff_mfma <<<1176,  256, 0, stream>>>(hpadh, hpadl, woffh, woffl, offb, pb1, pb2);
  k_offfix       <<<327,   256, 0, stream>>>(hpad, woff2, boff, offb);
  k_deform       <<<392,   256, 0, stream>>>(hpadh, offb, pb1, pb2, boff, w4f, out);
}

// Round 18
// 332.654 us; speedup vs baseline: 1.0889x; 1.0284x over previous
//
#include <hip/hip_runtime.h>
#include <hip/hip_bf16.h>

#define NP1 50176      // 224*224
#define NP2 12544      // 112*112
#define NPP 12996      // 114*114 zero-padded map

typedef __attribute__((ext_vector_type(8))) short short8;   // 8 bf16 = 4 VGPRs
typedef __attribute__((ext_vector_type(4))) float f32x4;

__device__ __forceinline__ unsigned short f2bu(float f){
  __hip_bfloat16 h = __float2bfloat16(f);
  return *reinterpret_cast<unsigned short*>(&h);
}
__device__ __forceinline__ float blo(unsigned u){ union{unsigned q; float f;} x; x.q = u<<16; return x.f; }
__device__ __forceinline__ float bhi(unsigned u){ union{unsigned q; float f;} x; x.q = u & 0xffff0000u; return x.f; }

// ---- workspace layout (float slots) ----
#define S_SUM1   0          // 128
#define S_SUM2   128        // 512
#define S_WOFF2  1280       // 73728 fp32 (k = n*256+c, oc padded 32)
#define S_W4F    75008      // 294912 (589824 bf16 frag-ready)
#define S_W2FH   369920     // 73728 (147456 bf16: w2 hi, frag-ready [kt][oc][kk], k=n*64+c)
#define S_W2FL   443648     // 73728 (147456 bf16: w2 lo)
#define S_OFFB   517376     // 451584 fp32 (NCHW; interior = convoff split-0 PARTIAL, band = exact)
#define S_PPAD   968960     // 1663488 fp32 (pooled NHWC [2][112][112][64]; DEAD after k_conv2 -> convoff split-1 partial)
#define S_HPAD   4295936    // 6653952 fp32 (NHWC padded; post-affine values only on border band)
#define S_HPADL  10949888   // 3326976 (6653952 bf16 NHWC lo)
#define S_WOFFH  14276864   // 36864 (73728 bf16 frag-ready hi)
#define S_WOFFL  14313728   // 36864 (73728 bf16 frag-ready lo)
#define S_PB2    14350592   // 451584 fp32 (convoff split-2 partial)
#define S_HPADH  15014144   // 3326976 (6653952 bf16 NHWC hi)
#define WS_NEED_FLOATS 18341120ull
#define WS_NEED_BYTES  (WS_NEED_FLOATS*4ull)   // 73.4 MB

// ---- conv1+bias+ReLU + 2x2 avgpool (16 oc/block), NHWC pooled output,
//      fused weight-prep prologue. grid 392 = 2b * 4ocg * 49tiles. ----
__global__ __launch_bounds__(256) void k_conv1pool(
    const float* __restrict__ x, const float* __restrict__ w1, const float* __restrict__ b1,
    float* __restrict__ pooled, float* __restrict__ sum1,
    const float* __restrict__ w4, const float* __restrict__ woff, const float* __restrict__ w2,
    unsigned short* __restrict__ w4f, float* __restrict__ woff2,
    unsigned short* __restrict__ woffh, unsigned short* __restrict__ woffl,
    unsigned short* __restrict__ w2fh, unsigned short* __restrict__ w2fl){
  // ---- prologue: grid-stride over 884736 weight-prep jobs ----
  for(int t0 = blockIdx.x*256+threadIdx.x; t0 < 884736; t0 += 392*256){
    if(t0 < 589824){
      int kt = t0/8192; int r = t0 - kt*8192;
      int oc = r>>5, kk = r&31;
      int k = kt*32 + kk; int n = k>>8, c = k&255;
      w4f[t0] = f2bu(w4[oc*2304 + c*9 + n]);
    } else if(t0 < 663552){
      int i2 = t0 - 589824;                    // 73728
      int k = i2>>5, oc = i2&31;
      int n = k>>8, c = k&255;
      woff2[i2] = (oc<18) ? woff[oc*2304 + c*9 + n] : 0.f;
    } else if(t0 < 737280){
      int i3 = t0 - 663552;                    // 73728
      int kt = i3>>10; int r = i3 & 1023;
      int oc = r>>5, kk = r&31;
      int k = kt*32 + kk; int n = k>>8, c = k&255;
      float wv = (oc<18) ? woff[oc*2304 + c*9 + n] : 0.f;
      unsigned short hi = f2bu(wv);
      woffh[i3] = hi;
      woffl[i3] = f2bu(wv - blo(hi));
    } else {
      int i4 = t0 - 737280;                    // 147456
      int kt = i4/8192; int r = i4 - kt*8192;
      int oc = r>>5, kk = r&31;
      int k = kt*32 + kk; int n = k>>6, c = k&63;
      float wv = w2[oc*576 + c*9 + n];
      unsigned short hi = f2bu(wv);
      w2fh[i4] = hi;
      w2fl[i4] = f2bu(wv - blo(hi));
    }
  }
  // ---- main: conv1 + pool (values bit-identical; output layout NHWC) ----
  __shared__ float xs[3*34*34];         // 13872 B
  __shared__ float ws[16*28];           // 16 oc x 27 taps (stride 28)
  __shared__ float wbia[16];
  __shared__ float red[4][32];          // [wave][stat*16+o]
  int bid = blockIdx.x;                 // 392
  int tile = bid % 49; int ocg = (bid/49) & 3; int b = bid/(49*4);
  int oc0 = ocg*16;
  int tu = tile/7, tv = tile - 7*(tile/7);
  int tid = threadIdx.x;
  int in0 = tu*32 - 1, jn0 = tv*32 - 1;
  for(int t=tid; t<3468; t+=256){
    int c = t/1156; int r2 = t - c*1156; int rr = r2/34; int cc = r2 - rr*34;
    int ii = in0+rr, jj = jn0+cc;
    xs[t] = (ii>=0 && ii<224 && jj>=0 && jj<224) ? x[(size_t)(b*3+c)*NP1 + ii*224+jj] : 0.f;
  }
  for(int t=tid; t<432; t+=256){
    int o = t/27, q = t - o*27;
    ws[o*28+q] = w1[(oc0+o)*27+q];
  }
  if(tid<16) wbia[tid] = b1[oc0+tid];
  __syncthreads();
  int u = tid>>4, v = tid&15;           // pooled coords in tile
  float xw[3][4][4];
  #pragma unroll
  for(int c=0;c<3;c++)
    #pragma unroll
    for(int r=0;r<4;r++)
      #pragma unroll
      for(int cc=0;cc<4;cc++)
        xw[c][r][cc] = xs[c*1156 + (2*u+r)*34 + (2*v+cc)];
  float s1o[16], s2o[16], pv[16];
  int U = tu*16+u, V = tv*16+v;
  #pragma unroll 1
  for(int o=0;o<16;o++){
    float w27[27];
    #pragma unroll
    for(int q=0;q<27;q++) w27[q] = ws[o*28+q];
    float bia = wbia[o];
    float pl=0.f, s1=0.f, s2=0.f;
    #pragma unroll
    for(int dy=0;dy<2;dy++){
      #pragma unroll
      for(int dx=0;dx<2;dx++){
        float acc = bia;
        #pragma unroll
        for(int c=0;c<3;c++)
          #pragma unroll
          for(int kh=0;kh<3;kh++)
            #pragma unroll
            for(int kw=0;kw<3;kw++)
              acc += xw[c][dy+kh][dx+kw] * w27[c*9+kh*3+kw];
        acc = fmaxf(acc, 0.f);          // relu BEFORE BN
        pl += acc; s1 += acc; s2 += acc*acc;
      }
    }
    pv[o] = 0.25f*pl;
    s1o[o] = s1; s2o[o] = s2;
  }
  // NHWC pooled store: 16 consecutive channels of this px -> 4x float4
  {
    float* dst = pooled + ((size_t)b*NP2 + U*112 + V)*64 + oc0;
    #pragma unroll
    for(int q4=0;q4<4;q4++){
      float4 o4; o4.x=pv[q4*4+0]; o4.y=pv[q4*4+1]; o4.z=pv[q4*4+2]; o4.w=pv[q4*4+3];
      *(float4*)(dst + q4*4) = o4;
    }
  }
  const int lane = tid&63, wv = tid>>6;
  #pragma unroll 1
  for(int o=0;o<16;o++){
    float a = s1o[o], c2 = s2o[o];
    #pragma unroll
    for(int off=32; off; off>>=1){
      a  += __shfl_down(a,  off, 64);
      c2 += __shfl_down(c2, off, 64);
    }
    if(lane==0){ red[wv][o] = a; red[wv][16+o] = c2; }
  }
  __syncthreads();
  if(tid<32){
    int o = tid&15, st = tid>>4;
    float v4 = ((red[0][st*16+o] + red[1][st*16+o]) + red[2][st*16+o]) + red[3][st*16+o];
    atomicAdd(&sum1[st*64 + oc0 + o], v4);
  }
}

// ---- conv2: MFMA bf16x2, M-tile 64, N=256, K=576.
//      BN1 affine + bf16 hi/lo split fused into STAGE; BN2 partial stats in epilogue. ----
__global__ __launch_bounds__(256) void k_conv2(
    const float* __restrict__ pooled,
    const float* __restrict__ sum1, const float* __restrict__ g1,
    const float* __restrict__ be1,
    const unsigned short* __restrict__ w2fh, const unsigned short* __restrict__ w2fl,
    const float* __restrict__ b2, float* __restrict__ hpad, float* __restrict__ sum2){
  __shared__ float smemf[8800];   // pp_tbl[576 ints] | af(5120 floats) ∪ tb(8224 floats)
  __shared__ float sc_l[64], sh_l[64];
  int*  pp_tbl = (int*)smemf;
  unsigned short* afh0 = (unsigned short*)(smemf + 576);    // 2*64*40 shorts = 2560 floats
  unsigned short* afl0 = (unsigned short*)(smemf + 576 + 2560);
  float* tb = smemf + 576;
  const int tid = threadIdx.x;
  const int wave = tid>>6, lane = tid&63;
  const int sidx = (blockIdx.x & 7)*49 + (blockIdx.x >> 3);  // XCD swizzle, grid 392
  const int pix0 = sidx*64;
  const int b = pix0/NP2, ij0 = pix0 - b*NP2;

  if(tid < 64){                         // BN1 stats, bit-identical to old k_fin1/affine1t
    float n = 2.f*(float)NP1;
    float mean = sum1[tid]/n;
    float var  = sum1[64+tid]/n - mean*mean;
    float sc = g1[tid]/sqrtf(var + 1e-5f);
    sc_l[tid] = sc;
    sh_l[tid] = be1[tid] - mean*sc;
  }
  for(int t=tid; t<576; t+=256){
    int p = t/9, n = t - 9*(t/9);
    int ij = ij0+p; int i = ij/112, j = ij - i*112;
    int pr = i + n/3, pc = j + n%3;     // padded coords 0..113
    bool bord = (pr==0) || (pr==113) || (pc==0) || (pc==113);
    pp_tbl[p*9+n] = bord ? -1 : ((pr-1)*112 + (pc-1));   // pooled px index or border flag
  }
  const int px_g = tid>>2;
  const int coff = (tid&3)*8;
  const float* po_b = pooled + (size_t)b*NP2*64;

  f32x4 acc[4][4] = {};
  __syncthreads();

  auto STAGE = [&](int kt, int buf){
    int n = kt>>1; int cb = ((kt&1)<<5) + coff;
    int pp = pp_tbl[px_g*9 + n];
    uint4 oh = {0u,0u,0u,0u}, ol = {0u,0u,0u,0u};       // border -> zeros (as affine1t did)
    if(pp >= 0){
      const float* src = po_b + (size_t)pp*64 + cb;
      float4 a4 = *(const float4*)src;
      float4 b4 = *(const float4*)(src+4);
      float v0 = sc_l[cb+0]*a4.x + sh_l[cb+0];
      float v1 = sc_l[cb+1]*a4.y + sh_l[cb+1];
      float v2 = sc_l[cb+2]*a4.z + sh_l[cb+2];
      float v3 = sc_l[cb+3]*a4.w + sh_l[cb+3];
      float v4 = sc_l[cb+4]*b4.x + sh_l[cb+4];
      float v5 = sc_l[cb+5]*b4.y + sh_l[cb+5];
      float v6 = sc_l[cb+6]*b4.z + sh_l[cb+6];
      float v7 = sc_l[cb+7]*b4.w + sh_l[cb+7];
      unsigned short h0=f2bu(v0), h1=f2bu(v1), h2=f2bu(v2), h3=f2bu(v3);
      unsigned short h4=f2bu(v4), h5=f2bu(v5), h6=f2bu(v6), h7=f2bu(v7);
      oh.x = (unsigned)h0 | ((unsigned)h1<<16);
      oh.y = (unsigned)h2 | ((unsigned)h3<<16);
      oh.z = (unsigned)h4 | ((unsigned)h5<<16);
      oh.w = (unsigned)h6 | ((unsigned)h7<<16);
      ol.x = (unsigned)f2bu(v0 - blo(h0)) | ((unsigned)f2bu(v1 - blo(h1))<<16);
      ol.y = (unsigned)f2bu(v2 - blo(h2)) | ((unsigned)f2bu(v3 - blo(h3))<<16);
      ol.z = (unsigned)f2bu(v4 - blo(h4)) | ((unsigned)f2bu(v5 - blo(h5))<<16);
      ol.w = (unsigned)f2bu(v6 - blo(h6)) | ((unsigned)f2bu(v7 - blo(h7))<<16);
    }
    *(uint4*)&afh0[buf*2560 + px_g*40 + coff] = oh;
    *(uint4*)&afl0[buf*2560 + px_g*40 + coff] = ol;
  };

  const int klo = (lane>>4)<<3;
  STAGE(0, 0);
  for(int kt=0; kt<18; kt++){
    __syncthreads();
    if(kt+1 < 18) STAGE(kt+1, (kt+1)&1);
    const unsigned short* abh = afh0 + (kt&1)*2560;
    const unsigned short* abl = afl0 + (kt&1)*2560;
    short8 aH[4], aL[4];
    #pragma unroll
    for(int mf=0; mf<4; mf++){
      aH[mf] = *(const short8*)&abh[(mf*16 + (lane&15))*40 + klo];
      aL[mf] = *(const short8*)&abl[(mf*16 + (lane&15))*40 + klo];
    }
    #pragma unroll
    for(int nf=0; nf<4; nf++){
      int oc = wave*64 + nf*16 + (lane&15);
      short8 bH = *(const short8*)&w2fh[(size_t)kt*8192 + oc*32 + klo];
      short8 bL = *(const short8*)&w2fl[(size_t)kt*8192 + oc*32 + klo];
      #pragma unroll
      for(int mf=0; mf<4; mf++){
        acc[mf][nf] = __builtin_amdgcn_mfma_f32_16x16x32_bf16(aH[mf], bH, acc[mf][nf], 0,0,0);
        acc[mf][nf] = __builtin_amdgcn_mfma_f32_16x16x32_bf16(aH[mf], bL, acc[mf][nf], 0,0,0);
        acc[mf][nf] = __builtin_amdgcn_mfma_f32_16x16x32_bf16(aL[mf], bH, acc[mf][nf], 0,0,0);
      }
    }
  }
  // epilogue: two 32-px halves through tb (bias+relu), NHWC float4 stores + BN2 partials
  const int row0 = (lane>>4)<<2, col = lane&15;
  float s1q[4] = {0.f,0.f,0.f,0.f}, s2q[4] = {0.f,0.f,0.f,0.f};
  for(int half=0; half<2; half++){
    __syncthreads();
    #pragma unroll
    for(int m2=0; m2<2; m2++){
      int mf = half*2 + m2;
      #pragma unroll
      for(int nf=0; nf<4; nf++){
        int oc = wave*64 + nf*16 + col;
        #pragma unroll
        for(int r=0;r<4;r++) tb[(m2*16 + row0 + r)*257 + oc] = acc[mf][nf][r];
      }
    }
    __syncthreads();
    #pragma unroll
    for(int it=0; it<8; it++){
      int id = it*256 + tid;
      int pxl = id>>6, oc4 = id&63;            // oc4 == tid&63 (constant per thread)
      int px = half*32 + pxl;
      int ij = ij0+px; int i = ij/112, j = ij - i*112;
      int pp = (i+1)*114 + (j+1);
      float4 v;
      v.x = fmaxf(tb[pxl*257 + oc4*4+0] + b2[oc4*4+0], 0.f);
      v.y = fmaxf(tb[pxl*257 + oc4*4+1] + b2[oc4*4+1], 0.f);
      v.z = fmaxf(tb[pxl*257 + oc4*4+2] + b2[oc4*4+2], 0.f);
      v.w = fmaxf(tb[pxl*257 + oc4*4+3] + b2[oc4*4+3], 0.f);
      *(float4*)&hpad[((size_t)b*NPP + pp)*256 + oc4*4] = v;   // raw (pre-BN2)
      s1q[0] += v.x; s2q[0] += v.x*v.x;
      s1q[1] += v.y; s2q[1] += v.y*v.y;
      s1q[2] += v.z; s2q[2] += v.z*v.z;
      s1q[3] += v.w; s2q[3] += v.w*v.w;
    }
  }
  // block-level BN2 partial reduce through tb, one atomic pair per oc
  __syncthreads();
  #pragma unroll
  for(int q=0;q<4;q++){ tb[tid*4+q] = s1q[q]; tb[1024 + tid*4+q] = s2q[q]; }
  __syncthreads();
  {
    int oc = tid;                               // 256 ocs
    float s1 = ((tb[oc] + tb[256+oc]) + tb[512+oc]) + tb[768+oc];
    float s2 = ((tb[1024+oc] + tb[1280+oc]) + tb[1536+oc]) + tb[1792+oc];
    atomicAdd(&sum2[oc], s1); atomicAdd(&sum2[256+oc], s2);
  }
}

// ---- BN2 stats (per-block, redundant) + affine, 4-ch vectorized; bf16 hi/lo; band fp32 ----
__global__ __launch_bounds__(256) void k_affine2(float* __restrict__ hpad,
                          const float* __restrict__ sum2, const float* __restrict__ g2,
                          const float* __restrict__ be2,
                          unsigned short* __restrict__ hpadh, unsigned short* __restrict__ hpadl){
  __shared__ float sc_l[256], sh_l[256];
  int tid = threadIdx.x;
  {                                     // bit-identical to old k_fin2
    float n = 2.f*(float)NP2;
    float mean = sum2[tid]/n;
    float var  = sum2[256+tid]/n - mean*mean;
    float sc = g2[tid]/sqrtf(var + 1e-5f);
    sc_l[tid] = sc;
    sh_l[tid] = be2[tid] - mean*sc;
  }
  __syncthreads();
  int idx = blockIdx.x*256+tid;            // 1663488 = 6498*256
  int c4 = (idx & 63) << 2;                // 0,4,..252
  int pi = idx >> 6;                       // 0..25991
  int pp = pi % NPP;
  int row = pp/114, col = pp - row*114;
  bool in = (row>=1 && row<=112 && col>=1 && col<=112);
  float4 h = *(const float4*)&hpad[(size_t)pi*256 + c4];
  float4 v;
  v.x = in ? (sc_l[c4+0]*h.x + sh_l[c4+0]) : 0.f;
  v.y = in ? (sc_l[c4+1]*h.y + sh_l[c4+1]) : 0.f;
  v.z = in ? (sc_l[c4+2]*h.z + sh_l[c4+2]) : 0.f;
  v.w = in ? (sc_l[c4+3]*h.w + sh_l[c4+3]) : 0.f;
  // fp32 hpad is only consumed by the offfix half on the border band
  bool band = (row<6) || (row>107) || (col<6) || (col>107);
  if(band) *(float4*)&hpad[(size_t)pi*256 + c4] = v;
  unsigned short hx = f2bu(v.x), hy = f2bu(v.y), hz = f2bu(v.z), hw = f2bu(v.w);
  uint2 oh, ol;
  oh.x = (unsigned)hx | ((unsigned)hy<<16);
  oh.y = (unsigned)hz | ((unsigned)hw<<16);
  ol.x = (unsigned)f2bu(v.x - blo(hx)) | ((unsigned)f2bu(v.y - blo(hy))<<16);
  ol.y = (unsigned)f2bu(v.z - blo(hz)) | ((unsigned)f2bu(v.w - blo(hw))<<16);
  *(uint2*)&hpadh[(size_t)pi*256 + c4] = oh;
  *(uint2*)&hpadl[(size_t)pi*256 + c4] = ol;
}

// ---- offset conv + border fix, ONE launch: grid 1503 = 1176 convoff + 327 offfix.
//      convoff: tap-split-K MFMA, 3 splits x 3 taps. split-0 skips band pixels
//      (band offb exclusively owned by the offfix blocks -> no race). ----
__global__ __launch_bounds__(256) void k_convoff_mfma(
    const unsigned short* __restrict__ hpadh, const unsigned short* __restrict__ hpadl,
    const unsigned short* __restrict__ woffh, const unsigned short* __restrict__ woffl,
    float* __restrict__ p0, float* __restrict__ p1, float* __restrict__ p2,
    const float* __restrict__ hpad, const float* __restrict__ woff2,
    const float* __restrict__ boff){
  const int tid = threadIdx.x;
  if(blockIdx.x >= 1176){
    // ---- offfix half: exact-fp32 recompute on the 3-wide border band ----
    int idx = (blockIdx.x - 1176)*256 + tid;  // 327*256 = 83712 = 2*1308*32
    if(idx >= 83712) return;
    int oc = idx & 31;
    int pid = idx >> 5;                       // 0..2615
    int b = pid / 1308; int t = pid - b*1308;
    int i, j;
    if(t < 672){                              // full rows 0,1,2,109,110,111
      int r = t/112; i = (r<3) ? r : 106+r; j = t - (t/112)*112;
    } else {                                  // cols 0,1,2,109,110,111 of rows 3..108
      int u = t - 672; i = 3 + u/6; int c6 = u - 6*(u/6);
      j = (c6<3) ? c6 : 106+c6;
    }
    const float* hb = hpad + (size_t)b*NPP*256;
    float a0=0.f, a1=0.f, a2=0.f, a3=0.f;     // 4 independent chains
    for(int n=0;n<9;n++){
      const float* ap = hb + (size_t)((i + n/3)*114 + (j + n%3))*256;
      const float* wp = woff2 + (size_t)n*256*32 + oc;
      #pragma unroll 4
      for(int c=0;c<256;c+=4){
        float4 a = *(const float4*)(ap + c);
        a0 = fmaf(a.x, wp[(c+0)*32], a0);
        a1 = fmaf(a.y, wp[(c+1)*32], a1);
        a2 = fmaf(a.z, wp[(c+2)*32], a2);
        a3 = fmaf(a.w, wp[(c+3)*32], a3);
      }
    }
    if(oc < 18)
      p0[(size_t)(b*18+oc)*NP2 + i*112 + j] = ((a0+a1)+(a2+a3)) + boff[oc];
    return;
  }
  // ---- convoff half ----
  __shared__ int pp_tbl[192];                              // 64 px x 3 taps
  __shared__ __align__(16) unsigned short afh[2][64*72];   // 18432 B
  __shared__ __align__(16) unsigned short afl[2][64*72];   // 18432 B
  const int wave = tid>>6, lane = tid&63;
  const int g = blockIdx.x;
  const int xcd = g & 7;
  const int rr  = g >> 3;               // 0..146
  const int split = rr % 3;             // k-split: taps split*3 .. +2
  const int sstrip = rr / 3;            // 0..48
  const int strip = xcd*49 + sstrip;    // 0..391
  const int pix0 = strip*64;
  const int b = pix0/NP2, ij0 = pix0 - b*NP2;
  const int n0 = split*3;

  for(int t=tid; t<192; t+=256){
    int p = t/3, nl = t - 3*(t/3);
    int ij = ij0+p; int i = ij/112, j = ij - i*112;
    int n = n0 + nl;
    pp_tbl[p*3+nl] = (i + n/3)*114 + (j + n%3);
  }
  const int px_g = tid>>2;              // 64 px, 4 thr/px
  const int coff = (tid&3)*16;          // 16-short (32B) slice of the 64-k phase
  const unsigned short* ph_b = hpadh + (size_t)b*NPP*256;
  const unsigned short* pl_b = hpadl + (size_t)b*NPP*256;
  const int r15 = lane&15, klo = (lane>>4)<<3;

  f32x4 acc[2] = {};
  __syncthreads();                      // pp_tbl ready

  auto STAGE = [&](int ph, int buf){    // ph = nl*4 + q : stages k = q*64..+63 of tap n0+nl
    int nl = ph>>2, q = ph&3;
    int pp = pp_tbl[px_g*3 + nl];
    int cb = q*64 + coff;
    uint4 h0 = *(const uint4*)(ph_b + (size_t)pp*256 + cb);
    uint4 h1 = *(const uint4*)(ph_b + (size_t)pp*256 + cb + 8);
    uint4 l0 = *(const uint4*)(pl_b + (size_t)pp*256 + cb);
    uint4 l1 = *(const uint4*)(pl_b + (size_t)pp*256 + cb + 8);
    *(uint4*)&afh[buf][px_g*72 + coff    ] = h0;
    *(uint4*)&afh[buf][px_g*72 + coff + 8] = h1;
    *(uint4*)&afl[buf][px_g*72 + coff    ] = l0;
    *(uint4*)&afl[buf][px_g*72 + coff + 8] = l1;
  };

  STAGE(0, 0);
  for(int ph=0; ph<12; ph++){
    __syncthreads();
    if(ph+1 < 12) STAGE(ph+1, (ph+1)&1);
    const unsigned short* ah = &afh[ph&1][(wave*16 + r15)*72];
    const unsigned short* al = &afl[ph&1][(wave*16 + r15)*72];
    const int n = n0 + (ph>>2), q = ph&3;
    #pragma unroll
    for(int half=0; half<2; half++){
      int kt = n*8 + q*2 + half;        // global k-tile index (B layout unchanged)
      short8 aH = *(const short8*)&ah[half*32 + klo];
      short8 aL = *(const short8*)&al[half*32 + klo];
      #pragma unroll
      for(int nf=0; nf<2; nf++){
        int oc = nf*16 + r15;
        short8 bH = *(const short8*)&woffh[(size_t)kt*1024 + oc*32 + klo];
        short8 bL = *(const short8*)&woffl[(size_t)kt*1024 + oc*32 + klo];
        acc[nf] = __builtin_amdgcn_mfma_f32_16x16x32_bf16(aH, bH, acc[nf], 0,0,0);
        acc[nf] = __builtin_amdgcn_mfma_f32_16x16x32_bf16(aH, bL, acc[nf], 0,0,0);
        acc[nf] = __builtin_amdgcn_mfma_f32_16x16x32_bf16(aL, bH, acc[nf], 0,0,0);
      }
    }
  }
  const int row0 = (lane>>4)<<2;
  #pragma unroll
  for(int nf=0; nf<2; nf++){
    int oc = nf*16 + r15;
    if(oc < 18){
      int ij = ij0 + wave*16 + row0;    // 4 consecutive px, same row (112%4==0)
      if(split != 0){
        float* dst = (split==1) ? p1 : p2;
        *(f32x4*)(dst + (size_t)(b*18+oc)*NP2 + ij) = acc[nf];
      } else {
        // split-0 -> offb: skip band pixels (owned by offfix blocks in this launch)
        int i = ij/112, j0v = ij - i*112;
        bool rowband = (i<3) || (i>108);
        if(!rowband && j0v>=4 && j0v<=104){
          *(f32x4*)(p0 + (size_t)(b*18+oc)*NP2 + ij) = acc[nf];
        } else {
          #pragma unroll
          for(int e=0;e<4;e++){
            int j = j0v+e;
            bool band = rowband || (j<3) || (j>108);
            if(!band) p0[(size_t)(b*18+oc)*NP2 + ij + e] = acc[nf][e];
          }
        }
      }
    }
  }
}

// ---- deformable conv: MFMA bf16, M-tile 64, 36 merged phases (k=64 each), grid 392 ----
// Prologue combines the 3 convoff k-split partials inline for interior pixels;
// band pixels read the exact-fp32 offb written by the offfix blocks.
__global__ __launch_bounds__(256) void k_deform(
    const unsigned short* __restrict__ hpadh,       // NHWC bf16, affine'd, zero border
    const float* __restrict__ offb,                 // split-0 partial (interior) / exact (band)
    const float* __restrict__ p1, const float* __restrict__ p2,
    const float* __restrict__ boff,
    const unsigned short* __restrict__ w4f,         // frag-ready bf16 [72][256][32]
    float* __restrict__ out){
  __shared__ int   gidx[64][9][4];
  __shared__ float gwt [64][9][4];
  __shared__ __align__(16) unsigned short afrag[2][64*72];  // px stride 72 shorts (bank-safe)
  const int tid = threadIdx.x;
  const int wave = tid>>6, lane = tid&63;
  const int sidx = (blockIdx.x & 7)*49 + (blockIdx.x >> 3);
  const int pix0 = sidx*64;
  const int b = pix0/NP2, ij0 = pix0 - b*NP2;

  for(int t=tid; t<576; t+=256){
    int p = t/9, n = t - 9*(t/9);
    int ij = ij0+p; int i = ij/112, j = ij - i*112;
    size_t bx = (size_t)(b*18 + 2*n  )*NP2 + ij;
    size_t by = (size_t)(b*18 + 2*n+1)*NP2 + ij;
    bool band = (i<3) || (i>108) || (j<3) || (j>108);
    float ox, oy;
    if(band){                           // exact values from the offfix blocks
      ox = offb[bx]; oy = offb[by];
    } else {                            // inline 3-split combine (same order as old reduce)
      ox = ((offb[bx] + p1[bx]) + p2[bx]) + boff[2*n];
      oy = ((offb[by] + p1[by]) + p2[by]) + boff[2*n+1];
    }
    float px = (float)(i + n/3) + ox;
    float py = (float)(j + n%3) + oy;
    float fpx = floorf(px), fpy = floorf(py);
    float qltxf = fminf(fmaxf(fpx,     0.f),113.f);
    float qltyf = fminf(fmaxf(fpy,     0.f),113.f);
    float qrbxf = fminf(fmaxf(fpx+1.f, 0.f),113.f);
    float qrbyf = fminf(fmaxf(fpy+1.f, 0.f),113.f);
    int qltx=(int)qltxf, qlty=(int)qltyf, qrbx=(int)qrbxf, qrby=(int)qrbyf;
    bool mx = (px<1.f)||(px>112.f);
    bool my = (py<1.f)||(py>112.f);
    float pxc = fminf(fmaxf(mx?fpx:px, 0.f),113.f);
    float pyc = fminf(fmaxf(my?fpy:py, 0.f),113.f);
    float glt = (1.f+(qltxf-pxc))*(1.f+(qltyf-pyc));
    float grb = (1.f-(qrbxf-pxc))*(1.f-(qrbyf-pyc));
    float glb = (1.f+(qltxf-pxc))*(1.f-(qrbyf-pyc));
    float grt = (1.f-(qrbxf-pxc))*(1.f+(qltyf-pyc));
    gidx[p][n][0]=qltx*114+qlty; gwt[p][n][0]=glt;
    gidx[p][n][1]=qrbx*114+qrby; gwt[p][n][1]=grb;
    gidx[p][n][2]=qltx*114+qrby; gwt[p][n][2]=glb;  // (lt_x, rb_y)
    gidx[p][n][3]=qrbx*114+qlty; gwt[p][n][3]=grt;  // (rb_x, lt_y)
  }

  const int px_g   = tid>>2;            // 0..63
  const int coff_g = (tid&3)*8;         // 8-channel slice within each 32-ch k-chunk
  const unsigned short* hb = hpadh + (size_t)b*NPP*256;

  f32x4 acc[4][4] = {};
  __syncthreads();

  // phase ph covers tap n = ph>>2, channels (ph&3)*64 .. +63
  auto GATHER = [&](int ph, int buf){
    int n = ph>>2; int qb = (ph&3)<<6;
    const int*   gi = gidx[px_g][n];
    const float* gw = gwt[px_g][n];
    int i0 = gi[0], i1 = gi[1], i2 = gi[2], i3 = gi[3];
    float w0 = gw[0], w1 = gw[1], w2 = gw[2], w3 = gw[3];
    #pragma unroll
    for(int h=0; h<2; h++){
      int cb = qb + h*32 + coff_g;
      f32x4 va = {0.f,0.f,0.f,0.f}, vb = {0.f,0.f,0.f,0.f};
      const uint4 u0 = *(const uint4*)(hb + (size_t)i0*256 + cb);
      const uint4 u1 = *(const uint4*)(hb + (size_t)i1*256 + cb);
      const uint4 u2 = *(const uint4*)(hb + (size_t)i2*256 + cb);
      const uint4 u3 = *(const uint4*)(hb + (size_t)i3*256 + cb);
      // per-channel corner order 0,1,2,3 — identical to the 32-k version
      va.x = fmaf(w0, blo(u0.x), va.x); va.y = fmaf(w0, bhi(u0.x), va.y);
      va.z = fmaf(w0, blo(u0.y), va.z); va.w = fmaf(w0, bhi(u0.y), va.w);
      vb.x = fmaf(w0, blo(u0.z), vb.x); vb.y = fmaf(w0, bhi(u0.z), vb.y);
      vb.z = fmaf(w0, blo(u0.w), vb.z); vb.w = fmaf(w0, bhi(u0.w), vb.w);
      va.x = fmaf(w1, blo(u1.x), va.x); va.y = fmaf(w1, bhi(u1.x), va.y);
      va.z = fmaf(w1, blo(u1.y), va.z); va.w = fmaf(w1, bhi(u1.y), va.w);
      vb.x = fmaf(w1, blo(u1.z), vb.x); vb.y = fmaf(w1, bhi(u1.z), vb.y);
      vb.z = fmaf(w1, blo(u1.w), vb.z); vb.w = fmaf(w1, bhi(u1.w), vb.w);
      va.x = fmaf(w2, blo(u2.x), va.x); va.y = fmaf(w2, bhi(u2.x), va.y);
      va.z = fmaf(w2, blo(u2.y), va.z); va.w = fmaf(w2, bhi(u2.y), va.w);
      vb.x = fmaf(w2, blo(u2.z), vb.x); vb.y = fmaf(w2, bhi(u2.z), vb.y);
      vb.z = fmaf(w2, blo(u2.w), vb.z); vb.w = fmaf(w2, bhi(u2.w), vb.w);
      va.x = fmaf(w3, blo(u3.x), va.x); va.y = fmaf(w3, bhi(u3.x), va.y);
      va.z = fmaf(w3, blo(u3.y), va.z); va.w = fmaf(w3, bhi(u3.y), va.w);
      vb.x = fmaf(w3, blo(u3.z), vb.x); vb.y = fmaf(w3, bhi(u3.z), vb.y);
      vb.z = fmaf(w3, blo(u3.w), vb.z); vb.w = fmaf(w3, bhi(u3.w), vb.w);
      uint4 o;
      o.x = (unsigned)f2bu(va.x) | ((unsigned)f2bu(va.y)<<16);
      o.y = (unsigned)f2bu(va.z) | ((unsigned)f2bu(va.w)<<16);
      o.z = (unsigned)f2bu(vb.x) | ((unsigned)f2bu(vb.y)<<16);
      o.w = (unsigned)f2bu(vb.z) | ((unsigned)f2bu(vb.w)<<16);
      *(uint4*)&afrag[buf][px_g*72 + h*32 + coff_g] = o;
    }
  };

  const int klo = (lane>>4)<<3;         // k-slice within a 32-k chunk
  GATHER(0, 0);
  for(int ph=0; ph<36; ph++){
    __syncthreads();
    if(ph+1 < 36) GATHER(ph+1, (ph+1)&1);
    const unsigned short* ab = afrag[ph&1];
    #pragma unroll
    for(int h=0; h<2; h++){
      int kt = (ph>>2)*8 + (ph&3)*2 + h;
      short8 aF[4];
      #pragma unroll
      for(int mf=0; mf<4; mf++)
        aF[mf] = *(const short8*)&ab[(mf*16 + (lane&15))*72 + h*32 + klo];
      const unsigned short* wb = w4f + (size_t)kt*8192 + klo;
      #pragma unroll
      for(int nf=0; nf<4; nf++){
        int oc = wave*64 + nf*16 + (lane&15);
        short8 bF = *(const short8*)&wb[oc*32];
        #pragma unroll
        for(int mf=0; mf<4; mf++)
          acc[mf][nf] = __builtin_amdgcn_mfma_f32_16x16x32_bf16(aF[mf], bF, acc[mf][nf], 0,0,0);
      }
    }
  }
  int row0 = ((lane>>4)<<2);
  int col  = lane&15;
  #pragma unroll
  for(int mf=0; mf<4; mf++)
    #pragma unroll
    for(int nf=0; nf<4; nf++){
      int oc = wave*64 + nf*16 + col;
      size_t ob = (size_t)(b*256+oc)*NP2 + ij0 + mf*16 + row0;
      *(f32x4*)(out + ob) = acc[mf][nf];
    }
}

extern "C" void kernel_launch(void* const* d_in, const int* in_sizes, int n_in,
                              void* d_out, int out_size, void* d_ws, size_t ws_size,
                              hipStream_t stream){
  (void)in_sizes; (void)n_in;
  const float* x    = (const float*)d_in[0];
  const float* w1   = (const float*)d_in[1];
  const float* b1   = (const float*)d_in[2];
  const float* g1   = (const float*)d_in[3];
  const float* be1  = (const float*)d_in[4];
  const float* w2   = (const float*)d_in[5];
  const float* b2   = (const float*)d_in[6];
  const float* g2   = (const float*)d_in[7];
  const float* be2  = (const float*)d_in[8];
  const float* woff = (const float*)d_in[9];
  const float* boff = (const float*)d_in[10];
  const float* w4   = (const float*)d_in[11];
  float* out = (float*)d_out;
  float* ws = (float*)d_ws;

  if(ws_size < WS_NEED_BYTES){
    hipMemsetAsync(d_out, 0, (size_t)out_size*sizeof(float), stream);
    return;
  }

  float* sum1   = ws + S_SUM1;
  float* sum2   = ws + S_SUM2;
  float* woff2  = ws + S_WOFF2;
  unsigned short* w4f   = (unsigned short*)(ws + S_W4F);
  unsigned short* w2fh  = (unsigned short*)(ws + S_W2FH);
  unsigned short* w2fl  = (unsigned short*)(ws + S_W2FL);
  unsigned short* woffh = (unsigned short*)(ws + S_WOFFH);
  unsigned short* woffl = (unsigned short*)(ws + S_WOFFL);
  float* offb   = ws + S_OFFB;
  float* pooled = ws + S_PPAD;          // pooled NHWC (dead before convoff writes pb1 here)
  float* pb1    = ws + S_PPAD;          // convoff split-1 partial
  float* pb2    = ws + S_PB2;           // convoff split-2 partial
  float* hpad   = ws + S_HPAD;
  unsigned short* hpadh = (unsigned short*)(ws + S_HPADH);
  unsigned short* hpadl = (unsigned short*)(ws + S_HPADL);

  hipMemsetAsync(sum1, 0, 640*sizeof(float), stream);   // sum1(128) + sum2(512)
  k_conv1pool    <<<392,   256, 0, stream>>>(x, w1, b1, pooled, sum1,
                                             w4, woff, w2, w4f, woff2, woffh, woffl,
                                             w2fh, w2fl);
  k_conv2        <<<392,   256, 0, stream>>>(pooled, sum1, g1, be1,
                                             w2fh, w2fl, b2, hpad, sum2);
  k_affine2      <<<6498,  256, 0, stream>>>(hpad, sum2, g2, be2, hpadh, hpadl);
  k_convoff_mfma <<<1503,  256, 0, stream>>>(hpadh, hpadl, woffh, woffl, offb, pb1, pb2,
                                             hpad, woff2, boff);
  k_deform       <<<392,   256, 0, stream>>>(hpadh, offb, pb1, pb2, boff, w4f, out);
}